// Round 4
// baseline (264.868 us; speedup 1.0000x reference)
//
#include <hip/hip_runtime.h>
#include <hip/hip_bf16.h>
#include <math.h>

#define B_   4
#define S_   2048
#define E_   256
#define H_   8
#define D_   32
#define FF_  1024
#define NTOK (B_*S_)   // 8192

typedef __attribute__((ext_vector_type(8))) short short8;
typedef __attribute__((ext_vector_type(4))) short s16x4;
typedef __attribute__((ext_vector_type(4))) float f32x4;
typedef __attribute__((ext_vector_type(4))) unsigned u32x4;
typedef __hip_bfloat16 bf16;

#define QSCALE 0.09016844005556021f   // (1/16) * log2(e)

__device__ __forceinline__ unsigned pack2_bf16(float a, float b) {
    unsigned ua = __builtin_bit_cast(unsigned, a);
    unsigned ub = __builtin_bit_cast(unsigned, b);
    ua = (ua + 0x7fffu + ((ua >> 16) & 1u)) >> 16;
    ub = (ub + 0x7fffu + ((ub >> 16) & 1u)) >> 16;
    return ua | (ub << 16);
}
__device__ __forceinline__ unsigned short round_bf16(float a) {
    unsigned ua = __builtin_bit_cast(unsigned, a);
    return (unsigned short)((ua + 0x7fffu + ((ua >> 16) & 1u)) >> 16);
}
__device__ __forceinline__ unsigned cvtpk_bf16(float lo, float hi) {
    unsigned r;
    asm("v_cvt_pk_bf16_f32 %0, %1, %2" : "=v"(r) : "v"(lo), "v"(hi));
    return r;
}
__device__ __forceinline__ void gld16(const short* g, short* l) {
    __builtin_amdgcn_global_load_lds(
        (const __attribute__((address_space(1))) unsigned int*)g,
        (__attribute__((address_space(3))) unsigned int*)l, 16, 0, 0);
}
// LDS tile layout: row stride 64 shorts (128B); 16B slot index = c16 ^ (row&7)
__device__ __forceinline__ short8 lds_frag(const short* base, int r, int c16) {
    return *(const short8*)(base + r*64 + (((c16) ^ (r & 7)) << 3));
}

// ---------------- weight convert+transpose: w[K][N] f32 -> wt[N][K] bf16 ----------------
__global__ __launch_bounds__(256) void wconv_kernel(
    const float* __restrict__ w, unsigned short* __restrict__ wt, int K, int N)
{
    __shared__ float tile[32][33];
    const int n0 = blockIdx.x * 32, k0 = blockIdx.y * 32;
    const int c = threadIdx.x & 31, r0 = threadIdx.x >> 5;   // r0: 0..7
    #pragma unroll
    for (int i = 0; i < 4; ++i)
        tile[r0 + 8*i][c] = w[(size_t)(k0 + r0 + 8*i)*N + n0 + c];
    __syncthreads();
    #pragma unroll
    for (int i = 0; i < 4; ++i)
        wt[(size_t)(n0 + r0 + 8*i)*K + k0 + c] = round_bf16(tile[c][r0 + 8*i]);
}

// ---------------- mask tile scan: mflags[b*32+t] = any-zero in mask[b][t*64..+63] ----------------
__global__ __launch_bounds__(128) void maskscan_kernel(
    const int* __restrict__ mask, int* __restrict__ mflags)
{
    const int t = threadIdx.x;   // 0..127 -> (b, tile)
    const int* p = mask + (t >> 5)*S_ + (t & 31)*64;
    int any0 = 0;
    #pragma unroll
    for (int i = 0; i < 16; ++i) {
        const int4 v = *(const int4*)(p + i*4);
        if (!(v.x && v.y && v.z && v.w)) any0 = 1;
    }
    mflags[t] = any0;
}

// ---------------- QKV projection -> bf16 [B,H,S,D] (Q pre-scaled by QSCALE) ----------------
__global__ __launch_bounds__(256) void qkv_kernel(
    const float* __restrict__ x,
    const float* __restrict__ wq, const float* __restrict__ wk, const float* __restrict__ wv,
    bf16* __restrict__ q, bf16* __restrict__ k, bf16* __restrict__ v)
{
    __shared__ float wqs[D_*D_], wks[D_*D_], wvs[D_*D_];
    __shared__ float xs[16][E_];
    const int tid = threadIdx.x;
    for (int i = tid; i < D_*D_; i += 256) {
        wqs[i] = wq[i]; wks[i] = wk[i]; wvs[i] = wv[i];
    }
    const int tok0 = blockIdx.x * 16;
    #pragma unroll
    for (int i = 0; i < 16; ++i)
        xs[i][tid] = x[(size_t)(tok0 + i)*E_ + tid];
    __syncthreads();
    const int h = tid >> 5, d = tid & 31;
    for (int t = 0; t < 16; ++t) {
        float aq = 0.f, ak = 0.f, av = 0.f;
        #pragma unroll
        for (int i = 0; i < D_; ++i) {
            const float xv = xs[t][h*D_ + i];
            aq += xv * wqs[i*D_ + d];
            ak += xv * wks[i*D_ + d];
            av += xv * wvs[i*D_ + d];
        }
        const int tok = tok0 + t;
        const int b = tok >> 11;
        const int s = tok & (S_-1);
        const size_t o = ((size_t)(b*H_ + h)*S_ + s)*D_ + d;
        q[o] = __float2bfloat16(aq * QSCALE);
        k[o] = __float2bfloat16(ak);
        v[o] = __float2bfloat16(av);
    }
}

// ---------------- V transpose: [B,H,S,D] -> VT [B,H,D,S] ----------------
__global__ __launch_bounds__(256) void vtrans_kernel(
    const short* __restrict__ v, short* __restrict__ vt)
{
    __shared__ short t2[D_][256];
    const int tid = threadIdx.x;
    const int bh = blockIdx.x >> 3;
    const int s0 = (blockIdx.x & 7) * 256;
    const short* src = v + ((size_t)bh*S_ + s0 + tid)*D_;
    const short8 r0 = *(const short8*)(src);
    const short8 r1 = *(const short8*)(src + 8);
    const short8 r2 = *(const short8*)(src + 16);
    const short8 r3 = *(const short8*)(src + 24);
    #pragma unroll
    for (int i = 0; i < 8; ++i) {
        t2[i     ][tid] = r0[i];
        t2[i + 8 ][tid] = r1[i];
        t2[i + 16][tid] = r2[i];
        t2[i + 24][tid] = r3[i];
    }
    __syncthreads();
    const int d = tid >> 3, j = tid & 7;
    short* dst = vt + ((size_t)(bh*D_ + d))*S_ + s0 + j*32;
    const short8* row = (const short8*)&t2[d][j*32];
    const short8 o0 = row[0], o1 = row[1], o2 = row[2], o3 = row[3];
    *(short8*)(dst     ) = o0;
    *(short8*)(dst + 8 ) = o1;
    *(short8*)(dst + 16) = o2;
    *(short8*)(dst + 24) = o3;
}

// ---------------- MFMA flash attention (shuffle-free P->PV, exp2 domain) ----------------
// scores^T = mfma(K_frag, Q_frag): sc[t][r] = score(key k0+16t+4g+r, query q0+col)
// PV B-frag slot (chunk c, kslot g*8+j) consumes key k0+32c+16*(j>>2)+4g+(j&3)
//   -> lane-local sc[2c+(j>>2)][j&3]; V A-frag loads the matching permuted keys.
__global__ __launch_bounds__(256) void attn_mfma_kernel(
    const short* __restrict__ qg, const short* __restrict__ kg,
    const short* __restrict__ vtg, const int* __restrict__ mask,
    const int* __restrict__ mflags, unsigned short* __restrict__ attn_out)
{
    const int lane = threadIdx.x & 63;
    const int wid  = threadIdx.x >> 6;
    const int col  = lane & 15;
    const int grp  = lane >> 4;
    // XCD swizzle: 1024 blocks, 8 XCDs -> all 32 blocks of one (b,h) on one XCD
    const int lb   = ((int)blockIdx.x & 7)*128 + ((int)blockIdx.x >> 3);
    const int bh   = lb >> 5;
    const int qt   = lb & 31;
    const int b    = bh >> 3;
    const int h    = bh & 7;
    const int q0   = qt*64 + wid*16;

    const short8 qf = *(const short8*)(qg + ((size_t)bh*S_ + q0 + col)*D_ + grp*8);
    const short* kbase = kg  + (size_t)bh*S_*D_;
    const short* vbase = vtg + (size_t)bh*D_*S_;
    const int*   mrow  = mask + b*S_;

    // per-tile "has masked key" bits
    const int fl = (lane < 32) ? mflags[b*32 + lane] : 0;
    const unsigned long long mbits = __ballot(fl != 0);

    f32x4 ot0 = {0.f,0.f,0.f,0.f}, ot1 = {0.f,0.f,0.f,0.f};
    const f32x4 zero = {0.f,0.f,0.f,0.f};
    float m = -3.0e38f, l = 0.f;

    for (int k0 = 0; k0 < S_; k0 += 64) {
        // ---- scores^T (4 x 16-key blocks), scale pre-folded into Q ----
        f32x4 s[4];
        #pragma unroll
        for (int t = 0; t < 4; ++t) {
            const short8 kf = *(const short8*)(kbase + (size_t)(k0 + t*16 + col)*D_ + grp*8);
            s[t] = __builtin_amdgcn_mfma_f32_16x16x32_bf16(kf, qf, zero, 0, 0, 0);
        }
        float sc[4][4];
        #pragma unroll
        for (int t = 0; t < 4; ++t)
            #pragma unroll
            for (int r = 0; r < 4; ++r) sc[t][r] = s[t][r];
        if ((mbits >> (k0 >> 6)) & 1ull) {
            #pragma unroll
            for (int t = 0; t < 4; ++t)
                #pragma unroll
                for (int r = 0; r < 4; ++r)
                    if (mrow[k0 + t*16 + grp*4 + r] == 0) sc[t][r] = -1e20f;
        }
        float pmax = sc[0][0];
        #pragma unroll
        for (int t = 0; t < 4; ++t)
            #pragma unroll
            for (int r = 0; r < 4; ++r) pmax = fmaxf(pmax, sc[t][r]);
        pmax = fmaxf(pmax, __shfl_xor(pmax, 16));
        pmax = fmaxf(pmax, __shfl_xor(pmax, 32));
        // ---- online softmax (log2 domain, defer-max THR=11.5) ----
        if (!__all(pmax - m <= 11.5f)) {
            const float mn = fmaxf(m, pmax);
            const float al = exp2f(m - mn);
            l *= al;
            #pragma unroll
            for (int r = 0; r < 4; ++r) { ot0[r] *= al; ot1[r] *= al; }
            m = mn;
        }
        float ps = 0.f;
        #pragma unroll
        for (int t = 0; t < 4; ++t)
            #pragma unroll
            for (int r = 0; r < 4; ++r) {
                sc[t][r] = exp2f(sc[t][r] - m);
                ps += sc[t][r];
            }
        ps += __shfl_xor(ps, 16);
        ps += __shfl_xor(ps, 32);
        l += ps;
        // ---- lane-local P pack -> B-frags (no cross-lane exchange) ----
        const u32x4 w0 = { cvtpk_bf16(sc[0][0], sc[0][1]), cvtpk_bf16(sc[0][2], sc[0][3]),
                           cvtpk_bf16(sc[1][0], sc[1][1]), cvtpk_bf16(sc[1][2], sc[1][3]) };
        const u32x4 w1 = { cvtpk_bf16(sc[2][0], sc[2][1]), cvtpk_bf16(sc[2][2], sc[2][3]),
                           cvtpk_bf16(sc[3][0], sc[3][1]), cvtpk_bf16(sc[3][2], sc[3][3]) };
        const short8 paf0 = __builtin_bit_cast(short8, w0);
        const short8 paf1 = __builtin_bit_cast(short8, w1);
        // ---- V loads in permuted slot order: kslot g*8+j <- key 32c+16*(j>>2)+4g+(j&3) ----
        const short* vr0 = vbase + (size_t)col*S_ + k0 + grp*4;
        const s16x4 a0 = *(const s16x4*)(vr0);
        const s16x4 a1 = *(const s16x4*)(vr0 + 16);
        const s16x4 a2 = *(const s16x4*)(vr0 + 32);
        const s16x4 a3 = *(const s16x4*)(vr0 + 48);
        const short8 vf0 = __builtin_shufflevector(a0, a1, 0,1,2,3,4,5,6,7);
        const short8 vf1 = __builtin_shufflevector(a2, a3, 0,1,2,3,4,5,6,7);
        ot0 = __builtin_amdgcn_mfma_f32_16x16x32_bf16(vf0, paf0, ot0, 0, 0, 0);
        ot0 = __builtin_amdgcn_mfma_f32_16x16x32_bf16(vf1, paf1, ot0, 0, 0, 0);
        const short* vr1 = vr0 + (size_t)16*S_;
        const s16x4 b0 = *(const s16x4*)(vr1);
        const s16x4 b1 = *(const s16x4*)(vr1 + 16);
        const s16x4 b2 = *(const s16x4*)(vr1 + 32);
        const s16x4 b3 = *(const s16x4*)(vr1 + 48);
        const short8 vf2 = __builtin_shufflevector(b0, b1, 0,1,2,3,4,5,6,7);
        const short8 vf3 = __builtin_shufflevector(b2, b3, 0,1,2,3,4,5,6,7);
        ot1 = __builtin_amdgcn_mfma_f32_16x16x32_bf16(vf2, paf0, ot1, 0, 0, 0);
        ot1 = __builtin_amdgcn_mfma_f32_16x16x32_bf16(vf3, paf1, ot1, 0, 0, 0);
    }
    const float inv = 1.0f / l;
    unsigned short* orow = attn_out + ((size_t)b*S_ + q0 + col)*E_ + h*D_ + grp*4;
    uint2 o0, o1;
    o0.x = pack2_bf16(ot0[0]*inv, ot0[1]*inv);
    o0.y = pack2_bf16(ot0[2]*inv, ot0[3]*inv);
    o1.x = pack2_bf16(ot1[0]*inv, ot1[1]*inv);
    o1.y = pack2_bf16(ot1[2]*inv, ot1[3]*inv);
    *(uint2*)(orow)      = o0;
    *(uint2*)(orow + 16) = o1;
}

// ---------------- bf16 MFMA GEMM: C[M,N] = op(A[M,K] @ WT[N,K]^T + bias) ----------------
// BM=128, BK=64, 256 thr = 4 waves (2x2). global_load_lds + XOR slot swizzle.
template<int BN, int RELU, int RESID, int WF32, int WBF16>
__global__ __launch_bounds__(256) void mgemm_kernel(
    const short* __restrict__ A, const short* __restrict__ WT,
    const float* __restrict__ bias, const float* __restrict__ R,
    float* __restrict__ C32, unsigned short* __restrict__ Cb,
    int M, int N, int K)
{
    constexpr int FC = BN / 32;
    __shared__ alignas(16) short As[128*64];
    __shared__ alignas(16) short Bs[BN*64];
    const int t = threadIdx.x, w = t >> 6, lane = t & 63;
    const int col = lane & 15, grp = lane >> 4;
    const int wm = w >> 1, wn = w & 1;
    const int bm = blockIdx.y, bn = blockIdx.x;
    const int arow = t >> 3, ac = t & 7;

    f32x4 acc[4][FC];
    #pragma unroll
    for (int i = 0; i < 4; ++i)
        #pragma unroll
        for (int j = 0; j < FC; ++j) acc[i][j] = (f32x4){0.f,0.f,0.f,0.f};

    for (int kb = 0; kb < K; kb += 64) {
        #pragma unroll
        for (int b2 = 0; b2 < 4; ++b2) {
            const int row = b2*32 + arow;
            gld16(A + (size_t)(bm*128 + row)*K + kb + ((ac ^ (row & 7)) << 3),
                  As + b2*2048 + w*512);
        }
        #pragma unroll
        for (int b2 = 0; b2 < BN/32; ++b2) {
            const int row = b2*32 + arow;
            gld16(WT + (size_t)(bn*BN + row)*K + kb + ((ac ^ (row & 7)) << 3),
                  Bs + b2*2048 + w*512);
        }
        __syncthreads();
        #pragma unroll
        for (int s = 0; s < 2; ++s) {
            short8 af[4], bf_[FC];
            #pragma unroll
            for (int fr = 0; fr < 4; ++fr)
                af[fr] = lds_frag(As, wm*64 + fr*16 + col, s*4 + grp);
            #pragma unroll
            for (int fc = 0; fc < FC; ++fc)
                bf_[fc] = lds_frag(Bs, wn*(BN/2) + fc*16 + col, s*4 + grp);
            #pragma unroll
            for (int fr = 0; fr < 4; ++fr)
                #pragma unroll
                for (int fc = 0; fc < FC; ++fc)
                    acc[fr][fc] = __builtin_amdgcn_mfma_f32_16x16x32_bf16(af[fr], bf_[fc], acc[fr][fc], 0, 0, 0);
        }
        __syncthreads();
    }

    #pragma unroll
    for (int fc = 0; fc < FC; ++fc) {
        const int n = bn*BN + wn*(BN/2) + fc*16 + col;
        const float bs = bias[n];
        #pragma unroll
        for (int fr = 0; fr < 4; ++fr) {
            #pragma unroll
            for (int reg = 0; reg < 4; ++reg) {
                const int m = bm*128 + wm*64 + fr*16 + grp*4 + reg;
                float v = acc[fr][fc][reg] + bs;
                if (RELU) v = fmaxf(v, 0.f);
                if (RESID) v += R[(size_t)m*N + n];
                if (WF32) C32[(size_t)m*N + n] = v;
                if (WBF16) Cb[(size_t)m*N + n] = round_bf16(v);
            }
        }
    }
}

// ---------------- series decomposition over E (window 25, edge pad) ----------------
template<int WF32, int WBF16>
__global__ __launch_bounds__(256) void decomp_kernel(
    const float* __restrict__ in, float* __restrict__ o32, unsigned short* __restrict__ ob)
{
    __shared__ float r[E_];
    const int row = blockIdx.x, e = threadIdx.x;
    const float xv = in[(size_t)row*E_ + e];
    r[e] = xv;
    __syncthreads();
    float sum = 0.f;
    #pragma unroll
    for (int j = -12; j <= 12; ++j) {
        int idx = e + j;
        idx = idx < 0 ? 0 : (idx > E_-1 ? E_-1 : idx);
        sum += r[idx];
    }
    const float res = xv - sum * (1.0f/25.0f);
    if (WF32) o32[(size_t)row*E_ + e] = res;
    if (WBF16) ob[(size_t)row*E_ + e] = round_bf16(res);
}

extern "C" void kernel_launch(void* const* d_in, const int* in_sizes, int n_in,
                              void* d_out, int out_size, void* d_ws, size_t ws_size,
                              hipStream_t stream) {
    const float* x     = (const float*)d_in[0];
    const int*   mask  = (const int*)  d_in[1];
    const float* wq    = (const float*)d_in[2];
    const float* wk    = (const float*)d_in[3];
    const float* wv    = (const float*)d_in[4];
    const float* w_out = (const float*)d_in[5];
    const float* b_out = (const float*)d_in[6];
    const float* ff_w1 = (const float*)d_in[7];
    const float* ff_b1 = (const float*)d_in[8];
    const float* ff_w2 = (const float*)d_in[9];
    const float* ff_b2 = (const float*)d_in[10];
    const float* pr_w1 = (const float*)d_in[11];
    const float* pr_b1 = (const float*)d_in[12];
    const float* pr_w2 = (const float*)d_in[13];
    const float* pr_b2 = (const float*)d_in[14];
    float* out = (float*)d_out;

    char* ws = (char*)d_ws;
    const size_t MB = 1024ull*1024ull;
    const size_t KB = 1024ull;
    bf16*  qb    = (bf16*)(ws + 0*MB);
    bf16*  kbf   = (bf16*)(ws + 4*MB);
    bf16*  vbf   = (bf16*)(ws + 8*MB);
    bf16*  vtb   = (bf16*)(ws + 12*MB);
    unsigned short* attnb = (unsigned short*)(ws + 16*MB);   // 4MB bf16
    float* x1    = (float*)(ws + 20*MB);                     // 8MB
    float* y32   = (float*)(ws + 28*MB);                     // 8MB
    unsigned short* yb  = (unsigned short*)(ws + 36*MB);     // 4MB
    unsigned short* h1  = (unsigned short*)(ws + 0*MB);      // 16MB (qkv dead)
    float* s32   = (float*)(ws + 20*MB);                     // 8MB (x1 dead)
    unsigned short* s2b = (unsigned short*)(ws + 16*MB);     // 4MB (attnb dead)
    unsigned short* h2  = (unsigned short*)(ws + 0*MB);      // 16MB (h1 dead)
    unsigned short* woT = (unsigned short*)(ws + 40*MB);                // 128KB
    unsigned short* f1T = (unsigned short*)(ws + 40*MB + 128*KB);       // 512KB
    unsigned short* f2T = (unsigned short*)(ws + 40*MB + 640*KB);       // 512KB
    unsigned short* p1T = (unsigned short*)(ws + 40*MB + 1152*KB);      // 512KB
    unsigned short* p2T = (unsigned short*)(ws + 40*MB + 1664*KB);      // 512KB
    int*            mfl = (int*)           (ws + 40*MB + 2176*KB);      // 512B

    // 0. weight convert+transpose (bf16) + mask tile scan
    wconv_kernel<<<dim3(E_/32,  E_/32),  256, 0, stream>>>(w_out, woT, E_,  E_);
    wconv_kernel<<<dim3(FF_/32, E_/32),  256, 0, stream>>>(ff_w1, f1T, E_,  FF_);
    wconv_kernel<<<dim3(E_/32,  FF_/32), 256, 0, stream>>>(ff_w2, f2T, FF_, E_);
    wconv_kernel<<<dim3(FF_/32, E_/32),  256, 0, stream>>>(pr_w1, p1T, E_,  FF_);
    wconv_kernel<<<dim3(E_/32,  FF_/32), 256, 0, stream>>>(pr_w2, p2T, FF_, E_);
    maskscan_kernel<<<1, 128, 0, stream>>>(mask, mfl);
    // 1. QKV (bf16, Q pre-scaled) + V transpose
    qkv_kernel<<<NTOK/16, 256, 0, stream>>>(x, wq, wk, wv, qb, kbf, vbf);
    vtrans_kernel<<<B_*H_*(S_/256), 256, 0, stream>>>((const short*)vbf, (short*)vtb);
    // 2. MFMA flash attention -> bf16
    attn_mfma_kernel<<<B_*H_*S_/64, 256, 0, stream>>>(
        (const short*)qb, (const short*)kbf, (const short*)vtb, mask, mfl, attnb);
    // 3. out-proj + residual: x1 = x + attn @ w_out + b_out   (fp32 out)
    mgemm_kernel<64,0,1,1,0><<<dim3(E_/64, NTOK/128), 256, 0, stream>>>(
        (const short*)attnb, (const short*)woT, b_out, x, x1, nullptr, NTOK, E_, E_);
    // 4. decomposition 1: y (fp32 + bf16)
    decomp_kernel<1,1><<<NTOK, 256, 0, stream>>>(x1, y32, yb);
    // 5. FFN
    mgemm_kernel<128,1,0,0,1><<<dim3(FF_/128, NTOK/128), 256, 0, stream>>>(
        (const short*)yb, (const short*)f1T, ff_b1, nullptr, nullptr, h1, NTOK, FF_, E_);
    mgemm_kernel<64,0,1,1,0><<<dim3(E_/64, NTOK/128), 256, 0, stream>>>(
        (const short*)h1, (const short*)f2T, ff_b2, y32, s32, nullptr, NTOK, E_, FF_);
    // 6. decomposition 2: s2 (bf16 only)
    decomp_kernel<0,1><<<NTOK, 256, 0, stream>>>(s32, nullptr, s2b);
    // 7. projection FFN
    mgemm_kernel<128,1,0,0,1><<<dim3(FF_/128, NTOK/128), 256, 0, stream>>>(
        (const short*)s2b, (const short*)p1T, pr_b1, nullptr, nullptr, h2, NTOK, FF_, E_);
    mgemm_kernel<64,0,0,1,0><<<dim3(E_/64, NTOK/128), 256, 0, stream>>>(
        (const short*)h2, (const short*)p2T, pr_b2, nullptr, out, nullptr, NTOK, E_, FF_);
}

// Round 5
// 209.330 us; speedup vs baseline: 1.2653x; 1.2653x over previous
//
#include <hip/hip_runtime.h>
#include <hip/hip_bf16.h>
#include <math.h>

#define B_   4
#define S_   2048
#define E_   256
#define H_   8
#define D_   32
#define FF_  1024
#define NTOK (B_*S_)   // 8192

typedef __attribute__((ext_vector_type(8))) short short8;
typedef __attribute__((ext_vector_type(4))) float f32x4;
typedef __attribute__((ext_vector_type(4))) unsigned u32x4;
typedef __hip_bfloat16 bf16;

#define QSCALE 0.09016844005556021f   // (1/16) * log2(e)

__device__ __forceinline__ unsigned short round_bf16(float a) {
    unsigned ua = __builtin_bit_cast(unsigned, a);
    return (unsigned short)((ua + 0x7fffu + ((ua >> 16) & 1u)) >> 16);
}
__device__ __forceinline__ unsigned cvtpk_bf16(float lo, float hi) {
    unsigned r;
    asm("v_cvt_pk_bf16_f32 %0, %1, %2" : "=v"(r) : "v"(lo), "v"(hi));
    return r;
}
__device__ __forceinline__ void gld16(const short* g, short* l) {
    __builtin_amdgcn_global_load_lds(
        (const __attribute__((address_space(1))) unsigned int*)g,
        (__attribute__((address_space(3))) unsigned int*)l, 16, 0, 0);
}
// LDS tile layout: row stride 64 shorts (128B); 16B slot index = c16 ^ (row&7)
__device__ __forceinline__ short8 lds_frag(const short* base, int r, int c16) {
    return *(const short8*)(base + r*64 + (((c16) ^ (r & 7)) << 3));
}

// ---------------- weight convert+transpose: w[K][N] f32 -> wt[N][K] bf16 ----------------
__global__ __launch_bounds__(256) void wconv_kernel(
    const float* __restrict__ w, unsigned short* __restrict__ wt, int K, int N)
{
    __shared__ float tile[32][33];
    const int n0 = blockIdx.x * 32, k0 = blockIdx.y * 32;
    const int c = threadIdx.x & 31, r0 = threadIdx.x >> 5;   // r0: 0..7
    #pragma unroll
    for (int i = 0; i < 4; ++i)
        tile[r0 + 8*i][c] = w[(size_t)(k0 + r0 + 8*i)*N + n0 + c];
    __syncthreads();
    #pragma unroll
    for (int i = 0; i < 4; ++i)
        wt[(size_t)(n0 + r0 + 8*i)*K + k0 + c] = round_bf16(tile[c][r0 + 8*i]);
}

// ---------------- mask tile scan: mflags[b*32+t] = any-zero in mask[b][t*64..+63] ----------------
__global__ __launch_bounds__(128) void maskscan_kernel(
    const int* __restrict__ mask, int* __restrict__ mflags)
{
    const int t = threadIdx.x;   // 0..127 -> (b, tile)
    const int* p = mask + (t >> 5)*S_ + (t & 31)*64;
    int any0 = 0;
    #pragma unroll
    for (int i = 0; i < 16; ++i) {
        const int4 v = *(const int4*)(p + i*4);
        if (!(v.x && v.y && v.z && v.w)) any0 = 1;
    }
    mflags[t] = any0;
}

// ---------------- QKV projection -> bf16 [B,H,S,D] ----------------
// Q pre-scaled by QSCALE. K stored PERMUTED within each 64-row tile:
// token u (=s&63) written to row 32*((u>>5)&1) + 16*((u>>2)&1) + 4*((u>>3)&3) + (u&3)
// so that reading row s yields key perm(s)=32c+8g+4a+b (s=32c+16a+4g+b).
__global__ __launch_bounds__(256) void qkv_kernel(
    const float* __restrict__ x,
    const float* __restrict__ wq, const float* __restrict__ wk, const float* __restrict__ wv,
    bf16* __restrict__ q, bf16* __restrict__ k, bf16* __restrict__ v)
{
    __shared__ float wqs[D_*D_], wks[D_*D_], wvs[D_*D_];
    __shared__ float xs[16][E_];
    const int tid = threadIdx.x;
    for (int i = tid; i < D_*D_; i += 256) {
        wqs[i] = wq[i]; wks[i] = wk[i]; wvs[i] = wv[i];
    }
    const int tok0 = blockIdx.x * 16;
    #pragma unroll
    for (int i = 0; i < 16; ++i)
        xs[i][tid] = x[(size_t)(tok0 + i)*E_ + tid];
    __syncthreads();
    const int h = tid >> 5, d = tid & 31;
    for (int t = 0; t < 16; ++t) {
        float aq = 0.f, ak = 0.f, av = 0.f;
        #pragma unroll
        for (int i = 0; i < D_; ++i) {
            const float xv = xs[t][h*D_ + i];
            aq += xv * wqs[i*D_ + d];
            ak += xv * wks[i*D_ + d];
            av += xv * wvs[i*D_ + d];
        }
        const int tok = tok0 + t;
        const int b = tok >> 11;
        const int s = tok & (S_-1);
        const int u = s & 63;
        const int sp = (s & ~63) | (((u>>5)&1)*32 + ((u>>2)&1)*16 + ((u>>3)&3)*4 + (u&3));
        const size_t base = (size_t)(b*H_ + h)*S_;
        q[(base + s )*D_ + d] = __float2bfloat16(aq * QSCALE);
        k[(base + sp)*D_ + d] = __float2bfloat16(ak);
        v[(base + s )*D_ + d] = __float2bfloat16(av);
    }
}

// ---------------- V transpose: [B,H,S,D] -> VT [B,H,D,S] ----------------
__global__ __launch_bounds__(256) void vtrans_kernel(
    const short* __restrict__ v, short* __restrict__ vt)
{
    __shared__ short t2[D_][256];
    const int tid = threadIdx.x;
    const int bh = blockIdx.x >> 3;
    const int s0 = (blockIdx.x & 7) * 256;
    const short* src = v + ((size_t)bh*S_ + s0 + tid)*D_;
    const short8 r0 = *(const short8*)(src);
    const short8 r1 = *(const short8*)(src + 8);
    const short8 r2 = *(const short8*)(src + 16);
    const short8 r3 = *(const short8*)(src + 24);
    #pragma unroll
    for (int i = 0; i < 8; ++i) {
        t2[i     ][tid] = r0[i];
        t2[i + 8 ][tid] = r1[i];
        t2[i + 16][tid] = r2[i];
        t2[i + 24][tid] = r3[i];
    }
    __syncthreads();
    const int d = tid >> 3, j = tid & 7;
    short* dst = vt + ((size_t)(bh*D_ + d))*S_ + s0 + j*32;
    const short8* row = (const short8*)&t2[d][j*32];
    const short8 o0 = row[0], o1 = row[1], o2 = row[2], o3 = row[3];
    *(short8*)(dst     ) = o0;
    *(short8*)(dst + 8 ) = o1;
    *(short8*)(dst + 16) = o2;
    *(short8*)(dst + 24) = o3;
}

// ---------------- MFMA flash attention ----------------
// Block = 4 waves = 2 q-groups x 2 key-halves (1024 keys each); LDS merge.
// K stored permuted so PV B-frag is lane-local AND V loads are 16B contiguous.
// sc[t][r] = score(physical key k0 + 32*(t>>1) + 8*grp + 4*(t&1) + r, query col).
__global__ __launch_bounds__(256) void attn_mfma_kernel(
    const short* __restrict__ qg, const short* __restrict__ kg,
    const short* __restrict__ vtg, const int* __restrict__ mask,
    const int* __restrict__ mflags, unsigned short* __restrict__ attn_out)
{
    __shared__ float mL[2][2][16];
    __shared__ float lL[2][2][16];
    __shared__ float oL[2][2][64][8];

    const int tid  = threadIdx.x;
    const int lane = tid & 63;
    const int wid  = tid >> 6;
    const int col  = lane & 15;
    const int grp  = lane >> 4;
    const int qs   = wid >> 1;     // q-group in block
    const int half = wid & 1;      // key half
    // XCD swizzle: 2048 blocks, 8 XCDs -> all 64 blocks of one (b,h) on one XCD
    const int p    = ((int)blockIdx.x & 7)*256 + ((int)blockIdx.x >> 3);
    const int bh   = p >> 6;
    const int pq   = p & 63;
    const int b    = bh >> 3;
    const int h    = bh & 7;
    const int q0   = (pq*2 + qs)*16;

    const short8 qf = *(const short8*)(qg + ((size_t)bh*S_ + q0 + col)*D_ + grp*8);
    const short* kbase = kg  + (size_t)bh*S_*D_;
    const short* vbase = vtg + (size_t)bh*D_*S_;
    const int*   mrow  = mask + b*S_;

    const int fl = (lane < 32) ? mflags[b*32 + lane] : 0;
    const unsigned long long mbits = __ballot(fl != 0);

    f32x4 ot0 = {0.f,0.f,0.f,0.f}, ot1 = {0.f,0.f,0.f,0.f};
    const f32x4 zero = {0.f,0.f,0.f,0.f};
    float m = 0.f, l = 0.f;   // log2-domain running max (per col), per-LANE partial sum

    const int k0beg = half*(S_/2), k0end = k0beg + S_/2;
    for (int k0 = k0beg; k0 < k0end; k0 += 64) {
        // ---- scores^T: 4 x 16-slot blocks (K rows pre-permuted) ----
        f32x4 s[4];
        #pragma unroll
        for (int t = 0; t < 4; ++t) {
            const short8 kf = *(const short8*)(kbase + (size_t)(k0 + t*16 + col)*D_ + grp*8);
            s[t] = __builtin_amdgcn_mfma_f32_16x16x32_bf16(kf, qf, zero, 0, 0, 0);
        }
        float sc[4][4];
        #pragma unroll
        for (int t = 0; t < 4; ++t)
            #pragma unroll
            for (int r = 0; r < 4; ++r) sc[t][r] = s[t][r];
        if ((mbits >> (k0 >> 6)) & 1ull) {
            #pragma unroll
            for (int t = 0; t < 4; ++t)
                #pragma unroll
                for (int r = 0; r < 4; ++r)
                    if (mrow[k0 + 32*(t>>1) + 8*grp + 4*(t&1) + r] == 0) sc[t][r] = -1e20f;
        }
        // ---- per-lane max; cross-lane reduce ONLY if defer threshold exceeded ----
        float pmax = sc[0][0];
        #pragma unroll
        for (int t = 0; t < 4; ++t)
            #pragma unroll
            for (int r = 0; r < 4; ++r) pmax = fmaxf(pmax, sc[t][r]);
        if (!__all(pmax - m <= 11.5f)) {
            pmax = fmaxf(pmax, __shfl_xor(pmax, 16));
            pmax = fmaxf(pmax, __shfl_xor(pmax, 32));
            const float mn = fmaxf(m, pmax);
            const float al = exp2f(m - mn);
            l *= al;
            #pragma unroll
            for (int r = 0; r < 4; ++r) { ot0[r] *= al; ot1[r] *= al; }
            m = mn;
        }
        #pragma unroll
        for (int t = 0; t < 4; ++t)
            #pragma unroll
            for (int r = 0; r < 4; ++r) {
                sc[t][r] = exp2f(sc[t][r] - m);
                l += sc[t][r];
            }
        // ---- lane-local P pack -> B-frags ----
        const u32x4 w0 = { cvtpk_bf16(sc[0][0], sc[0][1]), cvtpk_bf16(sc[0][2], sc[0][3]),
                           cvtpk_bf16(sc[1][0], sc[1][1]), cvtpk_bf16(sc[1][2], sc[1][3]) };
        const u32x4 w1 = { cvtpk_bf16(sc[2][0], sc[2][1]), cvtpk_bf16(sc[2][2], sc[2][3]),
                           cvtpk_bf16(sc[3][0], sc[3][1]), cvtpk_bf16(sc[3][2], sc[3][3]) };
        const short8 paf0 = __builtin_bit_cast(short8, w0);
        const short8 paf1 = __builtin_bit_cast(short8, w1);
        // ---- V: plain 16B contiguous loads (kslot g*8+j = physical key 32c+8g+j) ----
        const short* vr0 = vbase + (size_t)col*S_ + k0 + grp*8;
        const short8 vf0 = *(const short8*)(vr0);
        const short8 vf1 = *(const short8*)(vr0 + 32);
        ot0 = __builtin_amdgcn_mfma_f32_16x16x32_bf16(vf0, paf0, ot0, 0, 0, 0);
        ot0 = __builtin_amdgcn_mfma_f32_16x16x32_bf16(vf1, paf1, ot0, 0, 0, 0);
        const short* vr1 = vr0 + (size_t)16*S_;
        const short8 vf2 = *(const short8*)(vr1);
        const short8 vf3 = *(const short8*)(vr1 + 32);
        ot1 = __builtin_amdgcn_mfma_f32_16x16x32_bf16(vf2, paf0, ot1, 0, 0, 0);
        ot1 = __builtin_amdgcn_mfma_f32_16x16x32_bf16(vf3, paf1, ot1, 0, 0, 0);
    }
    // ---- reduce l over the 4 lane-groups (per query col) ----
    l += __shfl_xor(l, 16);
    l += __shfl_xor(l, 32);
    // ---- cross-wave merge of the two key halves via LDS ----
    if (grp == 0) { mL[qs][half][col] = m; lL[qs][half][col] = l; }
    #pragma unroll
    for (int r = 0; r < 4; ++r) {
        oL[qs][half][lane][r]     = ot0[r];
        oL[qs][half][lane][r + 4] = ot1[r];
    }
    __syncthreads();
    if (half == 0) {
        const float m1 = mL[qs][1][col];
        const float l1 = lL[qs][1][col];
        const float mS = fmaxf(m, m1);
        const float a0 = exp2f(m - mS), a1 = exp2f(m1 - mS);
        const float inv = 1.0f / (l*a0 + l1*a1);
        float w[8];
        #pragma unroll
        for (int r = 0; r < 4; ++r) {
            w[r]     = (ot0[r]*a0 + oL[qs][1][lane][r]    *a1) * inv;
            w[r + 4] = (ot1[r]*a0 + oL[qs][1][lane][r + 4]*a1) * inv;
        }
        unsigned short* orow = attn_out + ((size_t)b*S_ + q0 + col)*E_ + h*D_ + grp*4;
        uint2 o0, o1;
        o0.x = cvtpk_bf16(w[0], w[1]); o0.y = cvtpk_bf16(w[2], w[3]);
        o1.x = cvtpk_bf16(w[4], w[5]); o1.y = cvtpk_bf16(w[6], w[7]);
        *(uint2*)(orow)      = o0;
        *(uint2*)(orow + 16) = o1;
    }
}

// ---------------- bf16 MFMA GEMM: C[M,N] = op(A[M,K] @ WT[N,K]^T + bias) ----------------
// BM=128, BK=64, 256 thr = 4 waves (2x2). global_load_lds + XOR slot swizzle.
template<int BN, int RELU, int RESID, int WF32, int WBF16>
__global__ __launch_bounds__(256) void mgemm_kernel(
    const short* __restrict__ A, const short* __restrict__ WT,
    const float* __restrict__ bias, const float* __restrict__ R,
    float* __restrict__ C32, unsigned short* __restrict__ Cb,
    int M, int N, int K)
{
    constexpr int FC = BN / 32;
    __shared__ alignas(16) short As[128*64];
    __shared__ alignas(16) short Bs[BN*64];
    const int t = threadIdx.x, w = t >> 6, lane = t & 63;
    const int col = lane & 15, grp = lane >> 4;
    const int wm = w >> 1, wn = w & 1;
    const int bm = blockIdx.y, bn = blockIdx.x;
    const int arow = t >> 3, ac = t & 7;

    f32x4 acc[4][FC];
    #pragma unroll
    for (int i = 0; i < 4; ++i)
        #pragma unroll
        for (int j = 0; j < FC; ++j) acc[i][j] = (f32x4){0.f,0.f,0.f,0.f};

    for (int kb = 0; kb < K; kb += 64) {
        #pragma unroll
        for (int b2 = 0; b2 < 4; ++b2) {
            const int row = b2*32 + arow;
            gld16(A + (size_t)(bm*128 + row)*K + kb + ((ac ^ (row & 7)) << 3),
                  As + b2*2048 + w*512);
        }
        #pragma unroll
        for (int b2 = 0; b2 < BN/32; ++b2) {
            const int row = b2*32 + arow;
            gld16(WT + (size_t)(bn*BN + row)*K + kb + ((ac ^ (row & 7)) << 3),
                  Bs + b2*2048 + w*512);
        }
        __syncthreads();
        #pragma unroll
        for (int s = 0; s < 2; ++s) {
            short8 af[4], bf_[FC];
            #pragma unroll
            for (int fr = 0; fr < 4; ++fr)
                af[fr] = lds_frag(As, wm*64 + fr*16 + col, s*4 + grp);
            #pragma unroll
            for (int fc = 0; fc < FC; ++fc)
                bf_[fc] = lds_frag(Bs, wn*(BN/2) + fc*16 + col, s*4 + grp);
            #pragma unroll
            for (int fr = 0; fr < 4; ++fr)
                #pragma unroll
                for (int fc = 0; fc < FC; ++fc)
                    acc[fr][fc] = __builtin_amdgcn_mfma_f32_16x16x32_bf16(af[fr], bf_[fc], acc[fr][fc], 0, 0, 0);
        }
        __syncthreads();
    }

    #pragma unroll
    for (int fc = 0; fc < FC; ++fc) {
        const int n = bn*BN + wn*(BN/2) + fc*16 + col;
        const float bs = bias[n];
        #pragma unroll
        for (int fr = 0; fr < 4; ++fr) {
            #pragma unroll
            for (int reg = 0; reg < 4; ++reg) {
                const int m = bm*128 + wm*64 + fr*16 + grp*4 + reg;
                float v = acc[fr][fc][reg] + bs;
                if (RELU) v = fmaxf(v, 0.f);
                if (RESID) v += R[(size_t)m*N + n];
                if (WF32) C32[(size_t)m*N + n] = v;
                if (WBF16) Cb[(size_t)m*N + n] = round_bf16(v);
            }
        }
    }
}

// ---------------- series decomposition over E (window 25, edge pad) ----------------
template<int WF32, int WBF16>
__global__ __launch_bounds__(256) void decomp_kernel(
    const float* __restrict__ in, float* __restrict__ o32, unsigned short* __restrict__ ob)
{
    __shared__ float r[E_];
    const int row = blockIdx.x, e = threadIdx.x;
    const float xv = in[(size_t)row*E_ + e];
    r[e] = xv;
    __syncthreads();
    float sum = 0.f;
    #pragma unroll
    for (int j = -12; j <= 12; ++j) {
        int idx = e + j;
        idx = idx < 0 ? 0 : (idx > E_-1 ? E_-1 : idx);
        sum += r[idx];
    }
    const float res = xv - sum * (1.0f/25.0f);
    if (WF32) o32[(size_t)row*E_ + e] = res;
    if (WBF16) ob[(size_t)row*E_ + e] = round_bf16(res);
}

extern "C" void kernel_launch(void* const* d_in, const int* in_sizes, int n_in,
                              void* d_out, int out_size, void* d_ws, size_t ws_size,
                              hipStream_t stream) {
    const float* x     = (const float*)d_in[0];
    const int*   mask  = (const int*)  d_in[1];
    const float* wq    = (const float*)d_in[2];
    const float* wk    = (const float*)d_in[3];
    const float* wv    = (const float*)d_in[4];
    const float* w_out = (const float*)d_in[5];
    const float* b_out = (const float*)d_in[6];
    const float* ff_w1 = (const float*)d_in[7];
    const float* ff_b1 = (const float*)d_in[8];
    const float* ff_w2 = (const float*)d_in[9];
    const float* ff_b2 = (const float*)d_in[10];
    const float* pr_w1 = (const float*)d_in[11];
    const float* pr_b1 = (const float*)d_in[12];
    const float* pr_w2 = (const float*)d_in[13];
    const float* pr_b2 = (const float*)d_in[14];
    float* out = (float*)d_out;

    char* ws = (char*)d_ws;
    const size_t MB = 1024ull*1024ull;
    const size_t KB = 1024ull;
    bf16*  qb    = (bf16*)(ws + 0*MB);
    bf16*  kbf   = (bf16*)(ws + 4*MB);
    bf16*  vbf   = (bf16*)(ws + 8*MB);
    bf16*  vtb   = (bf16*)(ws + 12*MB);
    unsigned short* attnb = (unsigned short*)(ws + 16*MB);   // 4MB bf16
    float* x1    = (float*)(ws + 20*MB);                     // 8MB
    float* y32   = (float*)(ws + 28*MB);                     // 8MB
    unsigned short* yb  = (unsigned short*)(ws + 36*MB);     // 4MB
    unsigned short* h1  = (unsigned short*)(ws + 0*MB);      // 16MB (qkv dead)
    float* s32   = (float*)(ws + 20*MB);                     // 8MB (x1 dead)
    unsigned short* s2b = (unsigned short*)(ws + 16*MB);     // 4MB (attnb dead)
    unsigned short* h2  = (unsigned short*)(ws + 0*MB);      // 16MB (h1 dead)
    unsigned short* woT = (unsigned short*)(ws + 40*MB);                // 128KB
    unsigned short* f1T = (unsigned short*)(ws + 40*MB + 128*KB);       // 512KB
    unsigned short* f2T = (unsigned short*)(ws + 40*MB + 640*KB);       // 512KB
    unsigned short* p1T = (unsigned short*)(ws + 40*MB + 1152*KB);      // 512KB
    unsigned short* p2T = (unsigned short*)(ws + 40*MB + 1664*KB);      // 512KB
    int*            mfl = (int*)           (ws + 40*MB + 2176*KB);      // 512B

    // 0. weight convert+transpose (bf16) + mask tile scan
    wconv_kernel<<<dim3(E_/32,  E_/32),  256, 0, stream>>>(w_out, woT, E_,  E_);
    wconv_kernel<<<dim3(FF_/32, E_/32),  256, 0, stream>>>(ff_w1, f1T, E_,  FF_);
    wconv_kernel<<<dim3(E_/32,  FF_/32), 256, 0, stream>>>(ff_w2, f2T, FF_, E_);
    wconv_kernel<<<dim3(FF_/32, E_/32),  256, 0, stream>>>(pr_w1, p1T, E_,  FF_);
    wconv_kernel<<<dim3(E_/32,  FF_/32), 256, 0, stream>>>(pr_w2, p2T, FF_, E_);
    maskscan_kernel<<<1, 128, 0, stream>>>(mask, mfl);
    // 1. QKV (bf16, Q pre-scaled, K row-permuted) + V transpose
    qkv_kernel<<<NTOK/16, 256, 0, stream>>>(x, wq, wk, wv, qb, kbf, vbf);
    vtrans_kernel<<<B_*H_*(S_/256), 256, 0, stream>>>((const short*)vbf, (short*)vtb);
    // 2. MFMA flash attention -> bf16 (2 waves per q-group, split keys)
    attn_mfma_kernel<<<B_*H_*S_/32, 256, 0, stream>>>(
        (const short*)qb, (const short*)kbf, (const short*)vtb, mask, mfl, attnb);
    // 3. out-proj + residual: x1 = x + attn @ w_out + b_out   (fp32 out)
    mgemm_kernel<64,0,1,1,0><<<dim3(E_/64, NTOK/128), 256, 0, stream>>>(
        (const short*)attnb, (const short*)woT, b_out, x, x1, nullptr, NTOK, E_, E_);
    // 4. decomposition 1: y (fp32 + bf16)
    decomp_kernel<1,1><<<NTOK, 256, 0, stream>>>(x1, y32, yb);
    // 5. FFN
    mgemm_kernel<128,1,0,0,1><<<dim3(FF_/128, NTOK/128), 256, 0, stream>>>(
        (const short*)yb, (const short*)f1T, ff_b1, nullptr, nullptr, h1, NTOK, FF_, E_);
    mgemm_kernel<64,0,1,1,0><<<dim3(E_/64, NTOK/128), 256, 0, stream>>>(
        (const short*)h1, (const short*)f2T, ff_b2, y32, s32, nullptr, NTOK, E_, FF_);
    // 6. decomposition 2: s2 (bf16 only)
    decomp_kernel<0,1><<<NTOK, 256, 0, stream>>>(s32, nullptr, s2b);
    // 7. projection FFN
    mgemm_kernel<128,1,0,0,1><<<dim3(FF_/128, NTOK/128), 256, 0, stream>>>(
        (const short*)s2b, (const short*)p1T, pr_b1, nullptr, nullptr, h2, NTOK, FF_, E_);
    mgemm_kernel<64,0,0,1,0><<<dim3(E_/64, NTOK/128), 256, 0, stream>>>(
        (const short*)h2, (const short*)p2T, pr_b2, nullptr, out, nullptr, NTOK, E_, FF_);
}

// Round 6
// 157.652 us; speedup vs baseline: 1.6801x; 1.3278x over previous
//
#include <hip/hip_runtime.h>
#include <hip/hip_bf16.h>
#include <math.h>

#define B_   4
#define S_   2048
#define E_   256
#define H_   8
#define D_   32
#define FF_  1024
#define NTOK (B_*S_)   // 8192

typedef __attribute__((ext_vector_type(8))) short short8;
typedef __attribute__((ext_vector_type(4))) float f32x4;
typedef __attribute__((ext_vector_type(4))) unsigned u32x4;
typedef __hip_bfloat16 bf16;

#define QSCALE 0.09016844005556021f   // (1/16) * log2(e)

__device__ __forceinline__ unsigned short round_bf16(float a) {
    unsigned ua = __builtin_bit_cast(unsigned, a);
    return (unsigned short)((ua + 0x7fffu + ((ua >> 16) & 1u)) >> 16);
}
__device__ __forceinline__ unsigned cvtpk_bf16(float lo, float hi) {
    unsigned r;
    asm("v_cvt_pk_bf16_f32 %0, %1, %2" : "=v"(r) : "v"(lo), "v"(hi));
    return r;
}
__device__ __forceinline__ void gld16(const short* g, short* l) {
    __builtin_amdgcn_global_load_lds(
        (const __attribute__((address_space(1))) unsigned int*)g,
        (__attribute__((address_space(3))) unsigned int*)l, 16, 0, 0);
}
// GEMM LDS tile: row stride 64 shorts (128B); 16B slot index = c16 ^ (row&7)
__device__ __forceinline__ short8 lds_frag(const short* base, int r, int c16) {
    return *(const short8*)(base + r*64 + (((c16) ^ (r & 7)) << 3));
}

// ---------------- prep: 5x weight convert+transpose + mask tile scan ----------------
__global__ __launch_bounds__(256) void prep_kernel(
    const float* __restrict__ w_out, const float* __restrict__ ff_w1,
    const float* __restrict__ ff_w2, const float* __restrict__ pr_w1,
    const float* __restrict__ pr_w2,
    unsigned short* __restrict__ woT, unsigned short* __restrict__ f1T,
    unsigned short* __restrict__ f2T, unsigned short* __restrict__ p1T,
    unsigned short* __restrict__ p2T,
    const int* __restrict__ mask, int* __restrict__ mflags)
{
    const int bid = blockIdx.x;
    if (bid >= 1088) {   // maskscan
        const int t = threadIdx.x;
        if (t < 128) {
            const int* p = mask + (t >> 5)*S_ + (t & 31)*64;
            int any0 = 0;
            #pragma unroll
            for (int i = 0; i < 16; ++i) {
                const int4 v = *(const int4*)(p + i*4);
                if (!(v.x && v.y && v.z && v.w)) any0 = 1;
            }
            mflags[t] = any0;
        }
        return;
    }
    const float* w; unsigned short* wt; int K, N, idx;
    if (bid < 64)       { w = w_out; wt = woT; K = E_;  N = E_;  idx = bid; }
    else if (bid < 320) { w = ff_w1; wt = f1T; K = E_;  N = FF_; idx = bid - 64; }
    else if (bid < 576) { w = ff_w2; wt = f2T; K = FF_; N = E_;  idx = bid - 320; }
    else if (bid < 832) { w = pr_w1; wt = p1T; K = E_;  N = FF_; idx = bid - 576; }
    else                { w = pr_w2; wt = p2T; K = FF_; N = E_;  idx = bid - 832; }
    const int nb = N/32;
    const int n0 = (idx % nb)*32, k0 = (idx / nb)*32;
    __shared__ float tile[32][33];
    const int c = threadIdx.x & 31, r0 = threadIdx.x >> 5;
    #pragma unroll
    for (int i = 0; i < 4; ++i)
        tile[r0 + 8*i][c] = w[(size_t)(k0 + r0 + 8*i)*N + n0 + c];
    __syncthreads();
    #pragma unroll
    for (int i = 0; i < 4; ++i)
        wt[(size_t)(n0 + r0 + 8*i)*K + k0 + c] = round_bf16(tile[c][r0 + 8*i]);
}

// ---------------- QKV projection -> bf16 [B,H,S,D] ----------------
// Q pre-scaled by QSCALE. K stored PERMUTED within each 64-row tile:
// token u (=s&63) -> row 32*((u>>5)&1) + 16*((u>>2)&1) + 4*((u>>3)&3) + (u&3),
// so reading row s yields key perm(s)=32c+8g+4a+b (s=32c+16a+4g+b).
__global__ __launch_bounds__(256) void qkv_kernel(
    const float* __restrict__ x,
    const float* __restrict__ wq, const float* __restrict__ wk, const float* __restrict__ wv,
    bf16* __restrict__ q, bf16* __restrict__ k, bf16* __restrict__ v)
{
    __shared__ float wqs[D_*D_], wks[D_*D_], wvs[D_*D_];
    __shared__ float xs[16][E_];
    const int tid = threadIdx.x;
    for (int i = tid; i < D_*D_; i += 256) {
        wqs[i] = wq[i]; wks[i] = wk[i]; wvs[i] = wv[i];
    }
    const int tok0 = blockIdx.x * 16;
    #pragma unroll
    for (int i = 0; i < 16; ++i)
        xs[i][tid] = x[(size_t)(tok0 + i)*E_ + tid];
    __syncthreads();
    const int h = tid >> 5, d = tid & 31;
    for (int t = 0; t < 16; ++t) {
        float aq = 0.f, ak = 0.f, av = 0.f;
        #pragma unroll
        for (int i = 0; i < D_; ++i) {
            const float xv = xs[t][h*D_ + i];
            aq += xv * wqs[i*D_ + d];
            ak += xv * wks[i*D_ + d];
            av += xv * wvs[i*D_ + d];
        }
        const int tok = tok0 + t;
        const int b = tok >> 11;
        const int s = tok & (S_-1);
        const int u = s & 63;
        const int sp = (s & ~63) | (((u>>5)&1)*32 + ((u>>2)&1)*16 + ((u>>3)&3)*4 + (u&3));
        const size_t base = (size_t)(b*H_ + h)*S_;
        q[(base + s )*D_ + d] = __float2bfloat16(aq * QSCALE);
        k[(base + sp)*D_ + d] = __float2bfloat16(ak);
        v[(base + s )*D_ + d] = __float2bfloat16(av);
    }
}

// ---------------- V transpose: [B,H,S,D] -> VT [B,H,D,S] ----------------
__global__ __launch_bounds__(256) void vtrans_kernel(
    const short* __restrict__ v, short* __restrict__ vt)
{
    __shared__ short t2[D_][256];
    const int tid = threadIdx.x;
    const int bh = blockIdx.x >> 3;
    const int s0 = (blockIdx.x & 7) * 256;
    const short* src = v + ((size_t)bh*S_ + s0 + tid)*D_;
    const short8 r0 = *(const short8*)(src);
    const short8 r1 = *(const short8*)(src + 8);
    const short8 r2 = *(const short8*)(src + 16);
    const short8 r3 = *(const short8*)(src + 24);
    #pragma unroll
    for (int i = 0; i < 8; ++i) {
        t2[i     ][tid] = r0[i];
        t2[i + 8 ][tid] = r1[i];
        t2[i + 16][tid] = r2[i];
        t2[i + 24][tid] = r3[i];
    }
    __syncthreads();
    const int d = tid >> 3, j = tid & 7;
    short* dst = vt + ((size_t)(bh*D_ + d))*S_ + s0 + j*32;
    const short8* row = (const short8*)&t2[d][j*32];
    const short8 o0 = row[0], o1 = row[1], o2 = row[2], o3 = row[3];
    *(short8*)(dst     ) = o0;
    *(short8*)(dst + 8 ) = o1;
    *(short8*)(dst + 16) = o2;
    *(short8*)(dst + 24) = o3;
}

// ---------------- MFMA flash attention, LDS-staged K/V ----------------
// Block = 4 waves = 4 q-groups x 16 queries, all sharing one key stream.
// 32 tiles of 64 keys; K/V double-buffered in LDS via global_load_lds.
// K LDS [64 rows][32] (64B rows, 4 slots), read slot = g ^ ((c>>1)&3)  (conflict-free)
// V LDS [32 d][64 keys] (128B rows, 8 slots), read slot = s ^ (c&7)    (conflict-free)
// Sources are inverse-swizzled so the double-XOR cancels (rule: both-sides-or-neither).
// No max-tracking: P = exp2(sc) exactly (scores tiny; masked -> exp2(-1e20)=0).
__global__ __launch_bounds__(256) void attn_mfma_kernel(
    const short* __restrict__ qg, const short* __restrict__ kg,
    const short* __restrict__ vtg, const int* __restrict__ mask,
    const int* __restrict__ mflags, unsigned short* __restrict__ attn_out)
{
    __shared__ alignas(16) short lk[2][64*32];
    __shared__ alignas(16) short lv[2][32*64];

    const int tid  = threadIdx.x;
    const int lane = tid & 63;
    const int wid  = tid >> 6;
    const int c    = lane & 15;
    const int g    = lane >> 4;
    // XCD swizzle: 1024 blocks, 8 XCDs -> all 32 blocks of one (b,h) on one XCD
    const int p    = ((int)blockIdx.x & 7)*128 + ((int)blockIdx.x >> 3);
    const int bh   = p >> 5;
    const int qt   = p & 31;
    const int b    = bh >> 3;
    const int h    = bh & 7;
    const int q0   = qt*64 + wid*16;

    const short8 qf = *(const short8*)(qg + ((size_t)bh*S_ + q0 + c)*D_ + g*8);
    const short* kbase = kg  + (size_t)bh*S_*D_;
    const short* vbase = vtg + (size_t)bh*D_*S_;
    const int*   mrow  = mask + b*S_;

    const int fl = (lane < 32) ? mflags[b*32 + lane] : 0;
    const unsigned long long mbits = __ballot(fl != 0);

    // ---- staging plan: waves 0,1 -> K (16-row chunks), waves 2,3 -> V (8-row chunks)
    const short* sbase; int soff0, soff1, sinc, dchunk0;
    if (wid < 2) {
        const int R0 = wid*32 + (lane >> 2);
        const int R1 = R0 + 16;
        const int s  = lane & 3;
        soff0 = R0*D_ + ((s ^ ((R0 >> 1) & 3)) << 3);
        soff1 = R1*D_ + ((s ^ ((R1 >> 1) & 3)) << 3);
        sbase = kbase; sinc = 64*D_;
        dchunk0 = wid*1024;
    } else {
        const int r0 = (wid - 2)*16 + (lane >> 3);
        const int r1 = r0 + 8;
        const int s  = lane & 7;
        soff0 = r0*S_ + ((s ^ (r0 & 7)) << 3);
        soff1 = r1*S_ + ((s ^ (r1 & 7)) << 3);
        sbase = vbase; sinc = 64;
        dchunk0 = (wid - 2)*1024;
    }

    // ---- per-lane ds_read addresses (shorts)
    const int kaddr = c*D_ + ((g ^ ((c >> 1) & 3)) << 3);          // + t'*512 per frag
    const int va0   = c*64 + ((g       ^ (c & 7)) << 3);           // row c, keys 8g..
    const int va1   = c*64 + (((g + 4) ^ (c & 7)) << 3);           // row c, keys 32+8g..
    const f32x4 zero = {0.f,0.f,0.f,0.f};
    f32x4 ot0 = zero, ot1 = zero;
    float l = 0.f;

    // prologue: stage tile 0 into buf 0
    {
        short* d0 = (wid < 2 ? &lk[0][0] : &lv[0][0]) + dchunk0;
        gld16(sbase + soff0, d0);
        gld16(sbase + soff1, d0 + 512);
    }
    __syncthreads();

    int buf = 0;
    for (int t = 0; t < 32; ++t) {
        if (t < 31) {
            const short* sp = sbase + (size_t)(t + 1)*sinc;
            short* d0 = (wid < 2 ? &lk[buf ^ 1][0] : &lv[buf ^ 1][0]) + dchunk0;
            gld16(sp + soff0, d0);
            gld16(sp + soff1, d0 + 512);
        }
        const short* LK = &lk[buf][0];
        const short* LV = &lv[buf][0];
        // ---- QK^T (4 x 16-key-slot fragments) ----
        const short8 kf0 = *(const short8*)(LK + kaddr);
        const short8 kf1 = *(const short8*)(LK + kaddr + 512);
        const short8 kf2 = *(const short8*)(LK + kaddr + 1024);
        const short8 kf3 = *(const short8*)(LK + kaddr + 1536);
        f32x4 s0 = __builtin_amdgcn_mfma_f32_16x16x32_bf16(kf0, qf, zero, 0, 0, 0);
        f32x4 s1 = __builtin_amdgcn_mfma_f32_16x16x32_bf16(kf1, qf, zero, 0, 0, 0);
        f32x4 s2 = __builtin_amdgcn_mfma_f32_16x16x32_bf16(kf2, qf, zero, 0, 0, 0);
        f32x4 s3 = __builtin_amdgcn_mfma_f32_16x16x32_bf16(kf3, qf, zero, 0, 0, 0);
        // ---- mask (wave-uniform skip; key = 64t + 32*(t'>>1) + 8g + 4*(t'&1) + r) ----
        if ((mbits >> t) & 1ull) {
            const int kb = t*64 + 8*g;
            #pragma unroll
            for (int r = 0; r < 4; ++r) {
                if (mrow[kb      + r] == 0) s0[r] = -1e20f;
                if (mrow[kb + 4  + r] == 0) s1[r] = -1e20f;
                if (mrow[kb + 32 + r] == 0) s2[r] = -1e20f;
                if (mrow[kb + 36 + r] == 0) s3[r] = -1e20f;
            }
        }
        // ---- P = exp2(sc), l += sum ----
        float p00=exp2f(s0[0]), p01=exp2f(s0[1]), p02=exp2f(s0[2]), p03=exp2f(s0[3]);
        float p10=exp2f(s1[0]), p11=exp2f(s1[1]), p12=exp2f(s1[2]), p13=exp2f(s1[3]);
        float p20=exp2f(s2[0]), p21=exp2f(s2[1]), p22=exp2f(s2[2]), p23=exp2f(s2[3]);
        float p30=exp2f(s3[0]), p31=exp2f(s3[1]), p32=exp2f(s3[2]), p33=exp2f(s3[3]);
        l += ((p00+p01)+(p02+p03)) + ((p10+p11)+(p12+p13))
           + ((p20+p21)+(p22+p23)) + ((p30+p31)+(p32+p33));
        // ---- lane-local pack -> PV B-frags ----
        const u32x4 w0 = { cvtpk_bf16(p00,p01), cvtpk_bf16(p02,p03),
                           cvtpk_bf16(p10,p11), cvtpk_bf16(p12,p13) };
        const u32x4 w1 = { cvtpk_bf16(p20,p21), cvtpk_bf16(p22,p23),
                           cvtpk_bf16(p30,p31), cvtpk_bf16(p32,p33) };
        const short8 paf0 = __builtin_bit_cast(short8, w0);
        const short8 paf1 = __builtin_bit_cast(short8, w1);
        // ---- PV: V frags from LDS (swizzled, conflict-free) ----
        const short8 vf0 = *(const short8*)(LV + va0);
        const short8 vf1 = *(const short8*)(LV + va1);
        const short8 vf2 = *(const short8*)(LV + va0 + 1024);
        const short8 vf3 = *(const short8*)(LV + va1 + 1024);
        ot0 = __builtin_amdgcn_mfma_f32_16x16x32_bf16(vf0, paf0, ot0, 0, 0, 0);
        ot0 = __builtin_amdgcn_mfma_f32_16x16x32_bf16(vf1, paf1, ot0, 0, 0, 0);
        ot1 = __builtin_amdgcn_mfma_f32_16x16x32_bf16(vf2, paf0, ot1, 0, 0, 0);
        ot1 = __builtin_amdgcn_mfma_f32_16x16x32_bf16(vf3, paf1, ot1, 0, 0, 0);
        __syncthreads();
        buf ^= 1;
    }
    // ---- l over the 4 lane-groups, then write ----
    l += __shfl_xor(l, 16);
    l += __shfl_xor(l, 32);
    const float inv = 1.0f / l;
    unsigned short* orow = attn_out + ((size_t)b*S_ + q0 + c)*E_ + h*D_ + g*4;
    uint2 o0, o1;
    o0.x = cvtpk_bf16(ot0[0]*inv, ot0[1]*inv);
    o0.y = cvtpk_bf16(ot0[2]*inv, ot0[3]*inv);
    o1.x = cvtpk_bf16(ot1[0]*inv, ot1[1]*inv);
    o1.y = cvtpk_bf16(ot1[2]*inv, ot1[3]*inv);
    *(uint2*)(orow)      = o0;
    *(uint2*)(orow + 16) = o1;
}

// ---------------- bf16 MFMA GEMM: C[M,N] = op(A[M,K] @ WT[N,K]^T + bias) ----------------
template<int BN, int RELU, int RESID, int WF32, int WBF16>
__global__ __launch_bounds__(256) void mgemm_kernel(
    const short* __restrict__ A, const short* __restrict__ WT,
    const float* __restrict__ bias, const float* __restrict__ R,
    float* __restrict__ C32, unsigned short* __restrict__ Cb,
    int M, int N, int K)
{
    constexpr int FC = BN / 32;
    __shared__ alignas(16) short As[128*64];
    __shared__ alignas(16) short Bs[BN*64];
    const int t = threadIdx.x, w = t >> 6, lane = t & 63;
    const int col = lane & 15, grp = lane >> 4;
    const int wm = w >> 1, wn = w & 1;
    const int bm = blockIdx.y, bn = blockIdx.x;
    const int arow = t >> 3, ac = t & 7;

    f32x4 acc[4][FC];
    #pragma unroll
    for (int i = 0; i < 4; ++i)
        #pragma unroll
        for (int j = 0; j < FC; ++j) acc[i][j] = (f32x4){0.f,0.f,0.f,0.f};

    for (int kb = 0; kb < K; kb += 64) {
        #pragma unroll
        for (int b2 = 0; b2 < 4; ++b2) {
            const int row = b2*32 + arow;
            gld16(A + (size_t)(bm*128 + row)*K + kb + ((ac ^ (row & 7)) << 3),
                  As + b2*2048 + w*512);
        }
        #pragma unroll
        for (int b2 = 0; b2 < BN/32; ++b2) {
            const int row = b2*32 + arow;
            gld16(WT + (size_t)(bn*BN + row)*K + kb + ((ac ^ (row & 7)) << 3),
                  Bs + b2*2048 + w*512);
        }
        __syncthreads();
        #pragma unroll
        for (int s = 0; s < 2; ++s) {
            short8 af[4], bf_[FC];
            #pragma unroll
            for (int fr = 0; fr < 4; ++fr)
                af[fr] = lds_frag(As, wm*64 + fr*16 + col, s*4 + grp);
            #pragma unroll
            for (int fc = 0; fc < FC; ++fc)
                bf_[fc] = lds_frag(Bs, wn*(BN/2) + fc*16 + col, s*4 + grp);
            #pragma unroll
            for (int fr = 0; fr < 4; ++fr)
                #pragma unroll
                for (int fc = 0; fc < FC; ++fc)
                    acc[fr][fc] = __builtin_amdgcn_mfma_f32_16x16x32_bf16(af[fr], bf_[fc], acc[fr][fc], 0, 0, 0);
        }
        __syncthreads();
    }

    #pragma unroll
    for (int fc = 0; fc < FC; ++fc) {
        const int n = bn*BN + wn*(BN/2) + fc*16 + col;
        const float bs = bias[n];
        #pragma unroll
        for (int fr = 0; fr < 4; ++fr) {
            #pragma unroll
            for (int reg = 0; reg < 4; ++reg) {
                const int m = bm*128 + wm*64 + fr*16 + grp*4 + reg;
                float v = acc[fr][fc][reg] + bs;
                if (RELU) v = fmaxf(v, 0.f);
                if (RESID) v += R[(size_t)m*N + n];
                if (WF32) C32[(size_t)m*N + n] = v;
                if (WBF16) Cb[(size_t)m*N + n] = round_bf16(v);
            }
        }
    }
}

// ---------------- series decomposition over E (window 25, edge pad) ----------------
template<int WF32, int WBF16>
__global__ __launch_bounds__(256) void decomp_kernel(
    const float* __restrict__ in, float* __restrict__ o32, unsigned short* __restrict__ ob)
{
    __shared__ float r[E_];
    const int row = blockIdx.x, e = threadIdx.x;
    const float xv = in[(size_t)row*E_ + e];
    r[e] = xv;
    __syncthreads();
    float sum = 0.f;
    #pragma unroll
    for (int j = -12; j <= 12; ++j) {
        int idx = e + j;
        idx = idx < 0 ? 0 : (idx > E_-1 ? E_-1 : idx);
        sum += r[idx];
    }
    const float res = xv - sum * (1.0f/25.0f);
    if (WF32) o32[(size_t)row*E_ + e] = res;
    if (WBF16) ob[(size_t)row*E_ + e] = round_bf16(res);
}

extern "C" void kernel_launch(void* const* d_in, const int* in_sizes, int n_in,
                              void* d_out, int out_size, void* d_ws, size_t ws_size,
                              hipStream_t stream) {
    const float* x     = (const float*)d_in[0];
    const int*   mask  = (const int*)  d_in[1];
    const float* wq    = (const float*)d_in[2];
    const float* wk    = (const float*)d_in[3];
    const float* wv    = (const float*)d_in[4];
    const float* w_out = (const float*)d_in[5];
    const float* b_out = (const float*)d_in[6];
    const float* ff_w1 = (const float*)d_in[7];
    const float* ff_b1 = (const float*)d_in[8];
    const float* ff_w2 = (const float*)d_in[9];
    const float* ff_b2 = (const float*)d_in[10];
    const float* pr_w1 = (const float*)d_in[11];
    const float* pr_b1 = (const float*)d_in[12];
    const float* pr_w2 = (const float*)d_in[13];
    const float* pr_b2 = (const float*)d_in[14];
    float* out = (float*)d_out;

    char* ws = (char*)d_ws;
    const size_t MB = 1024ull*1024ull;
    const size_t KB = 1024ull;
    bf16*  qb    = (bf16*)(ws + 0*MB);
    bf16*  kbf   = (bf16*)(ws + 4*MB);
    bf16*  vbf   = (bf16*)(ws + 8*MB);
    bf16*  vtb   = (bf16*)(ws + 12*MB);
    unsigned short* attnb = (unsigned short*)(ws + 16*MB);   // 4MB bf16
    float* x1    = (float*)(ws + 20*MB);                     // 8MB
    float* y32   = (float*)(ws + 28*MB);                     // 8MB
    unsigned short* yb  = (unsigned short*)(ws + 36*MB);     // 4MB
    unsigned short* h1  = (unsigned short*)(ws + 0*MB);      // 16MB (qkv dead)
    float* s32   = (float*)(ws + 20*MB);                     // 8MB (x1 dead)
    unsigned short* s2b = (unsigned short*)(ws + 16*MB);     // 4MB (attnb dead)
    unsigned short* h2  = (unsigned short*)(ws + 0*MB);      // 16MB (h1 dead)
    unsigned short* woT = (unsigned short*)(ws + 40*MB);                // 128KB
    unsigned short* f1T = (unsigned short*)(ws + 40*MB + 128*KB);       // 512KB
    unsigned short* f2T = (unsigned short*)(ws + 40*MB + 640*KB);       // 512KB
    unsigned short* p1T = (unsigned short*)(ws + 40*MB + 1152*KB);      // 512KB
    unsigned short* p2T = (unsigned short*)(ws + 40*MB + 1664*KB);      // 512KB
    int*            mfl = (int*)           (ws + 40*MB + 2176*KB);      // 512B

    // 0. fused weight convert+transpose + mask tile scan
    prep_kernel<<<1089, 256, 0, stream>>>(w_out, ff_w1, ff_w2, pr_w1, pr_w2,
                                          woT, f1T, f2T, p1T, p2T, mask, mfl);
    // 1. QKV (bf16, Q pre-scaled, K row-permuted) + V transpose
    qkv_kernel<<<NTOK/16, 256, 0, stream>>>(x, wq, wk, wv, qb, kbf, vbf);
    vtrans_kernel<<<B_*H_*(S_/256), 256, 0, stream>>>((const short*)vbf, (short*)vtb);
    // 2. MFMA flash attention (LDS-staged K/V, 64 q per block) -> bf16
    attn_mfma_kernel<<<B_*H_*S_/64, 256, 0, stream>>>(
        (const short*)qb, (const short*)kbf, (const short*)vtb, mask, mfl, attnb);
    // 3. out-proj + residual: x1 = x + attn @ w_out + b_out   (fp32 out)
    mgemm_kernel<64,0,1,1,0><<<dim3(E_/64, NTOK/128), 256, 0, stream>>>(
        (const short*)attnb, (const short*)woT, b_out, x, x1, nullptr, NTOK, E_, E_);
    // 4. decomposition 1: y (fp32 + bf16)
    decomp_kernel<1,1><<<NTOK, 256, 0, stream>>>(x1, y32, yb);
    // 5. FFN
    mgemm_kernel<128,1,0,0,1><<<dim3(FF_/128, NTOK/128), 256, 0, stream>>>(
        (const short*)yb, (const short*)f1T, ff_b1, nullptr, nullptr, h1, NTOK, FF_, E_);
    mgemm_kernel<64,0,1,1,0><<<dim3(E_/64, NTOK/128), 256, 0, stream>>>(
        (const short*)h1, (const short*)f2T, ff_b2, y32, s32, nullptr, NTOK, E_, FF_);
    // 6. decomposition 2: s2 (bf16 only)
    decomp_kernel<0,1><<<NTOK, 256, 0, stream>>>(s32, nullptr, s2b);
    // 7. projection FFN
    mgemm_kernel<128,1,0,0,1><<<dim3(FF_/128, NTOK/128), 256, 0, stream>>>(
        (const short*)s2b, (const short*)p1T, pr_b1, nullptr, nullptr, h2, NTOK, FF_, E_);
    mgemm_kernel<64,0,0,1,0><<<dim3(E_/64, NTOK/128), 256, 0, stream>>>(
        (const short*)h2, (const short*)p2T, pr_b2, nullptr, out, nullptr, NTOK, E_, FF_);
}

// Round 7
// 129.337 us; speedup vs baseline: 2.0479x; 1.2189x over previous
//
#include <hip/hip_runtime.h>
#include <hip/hip_bf16.h>
#include <math.h>

#define B_   4
#define S_   2048
#define E_   256
#define H_   8
#define D_   32
#define FF_  1024
#define NTOK (B_*S_)   // 8192

typedef __attribute__((ext_vector_type(8))) short short8;
typedef __attribute__((ext_vector_type(4))) float f32x4;
typedef __attribute__((ext_vector_type(4))) unsigned u32x4;
typedef __hip_bfloat16 bf16;

#define QSCALE 0.09016844005556021f   // (1/16) * log2(e)

__device__ __forceinline__ unsigned short round_bf16(float a) {
    unsigned ua = __builtin_bit_cast(unsigned, a);
    return (unsigned short)((ua + 0x7fffu + ((ua >> 16) & 1u)) >> 16);
}
__device__ __forceinline__ unsigned cvtpk_bf16(float lo, float hi) {
    unsigned r;
    asm("v_cvt_pk_bf16_f32 %0, %1, %2" : "=v"(r) : "v"(lo), "v"(hi));
    return r;
}
__device__ __forceinline__ float fexp2(float x) {
    float r;
    asm("v_exp_f32 %0, %1" : "=v"(r) : "v"(x));
    return r;
}
__device__ __forceinline__ void gld16(const short* g, short* l) {
    __builtin_amdgcn_global_load_lds(
        (const __attribute__((address_space(1))) unsigned int*)g,
        (__attribute__((address_space(3))) unsigned int*)l, 16, 0, 0);
}
// GEMM LDS tile: row stride 64 shorts (128B); 16B slot index = c16 ^ (row&7)
__device__ __forceinline__ short8 lds_frag(const short* base, int r, int c16) {
    return *(const short8*)(base + r*64 + (((c16) ^ (r & 7)) << 3));
}

// ---------------- prep: 5x weight convert+transpose + mask tile scan ----------------
__global__ __launch_bounds__(256) void prep_kernel(
    const float* __restrict__ w_out, const float* __restrict__ ff_w1,
    const float* __restrict__ ff_w2, const float* __restrict__ pr_w1,
    const float* __restrict__ pr_w2,
    unsigned short* __restrict__ woT, unsigned short* __restrict__ f1T,
    unsigned short* __restrict__ f2T, unsigned short* __restrict__ p1T,
    unsigned short* __restrict__ p2T,
    const int* __restrict__ mask, int* __restrict__ mflags)
{
    const int bid = blockIdx.x;
    if (bid >= 1088) {   // maskscan
        const int t = threadIdx.x;
        if (t < 128) {
            const int* p = mask + (t >> 5)*S_ + (t & 31)*64;
            int any0 = 0;
            #pragma unroll
            for (int i = 0; i < 16; ++i) {
                const int4 v = *(const int4*)(p + i*4);
                if (!(v.x && v.y && v.z && v.w)) any0 = 1;
            }
            mflags[t] = any0;
        }
        return;
    }
    const float* w; unsigned short* wt; int K, N, idx;
    if (bid < 64)       { w = w_out; wt = woT; K = E_;  N = E_;  idx = bid; }
    else if (bid < 320) { w = ff_w1; wt = f1T; K = E_;  N = FF_; idx = bid - 64; }
    else if (bid < 576) { w = ff_w2; wt = f2T; K = FF_; N = E_;  idx = bid - 320; }
    else if (bid < 832) { w = pr_w1; wt = p1T; K = E_;  N = FF_; idx = bid - 576; }
    else                { w = pr_w2; wt = p2T; K = FF_; N = E_;  idx = bid - 832; }
    const int nb = N/32;
    const int n0 = (idx % nb)*32, k0 = (idx / nb)*32;
    __shared__ float tile[32][33];
    const int c = threadIdx.x & 31, r0 = threadIdx.x >> 5;
    #pragma unroll
    for (int i = 0; i < 4; ++i)
        tile[r0 + 8*i][c] = w[(size_t)(k0 + r0 + 8*i)*N + n0 + c];
    __syncthreads();
    #pragma unroll
    for (int i = 0; i < 4; ++i)
        wt[(size_t)(n0 + r0 + 8*i)*K + k0 + c] = round_bf16(tile[c][r0 + 8*i]);
}

// ---------------- QKV projection -> bf16 [B,H,S,D] ----------------
// Q pre-scaled by QSCALE. K stored PERMUTED within each 64-row tile:
// token u (=s&63) -> row 32*((u>>5)&1) + 16*((u>>2)&1) + 4*((u>>3)&3) + (u&3),
// so reading row s yields key perm(s)=32c+8g+4a+b (s=32c+16a+4g+b).
__global__ __launch_bounds__(256) void qkv_kernel(
    const float* __restrict__ x,
    const float* __restrict__ wq, const float* __restrict__ wk, const float* __restrict__ wv,
    bf16* __restrict__ q, bf16* __restrict__ k, bf16* __restrict__ v)
{
    __shared__ float wqs[D_*D_], wks[D_*D_], wvs[D_*D_];
    __shared__ float xs[16][E_];
    const int tid = threadIdx.x;
    for (int i = tid; i < D_*D_; i += 256) {
        wqs[i] = wq[i]; wks[i] = wk[i]; wvs[i] = wv[i];
    }
    const int tok0 = blockIdx.x * 16;
    #pragma unroll
    for (int i = 0; i < 16; ++i)
        xs[i][tid] = x[(size_t)(tok0 + i)*E_ + tid];
    __syncthreads();
    const int h = tid >> 5, d = tid & 31;
    for (int t = 0; t < 16; ++t) {
        float aq = 0.f, ak = 0.f, av = 0.f;
        #pragma unroll
        for (int i = 0; i < D_; ++i) {
            const float xv = xs[t][h*D_ + i];
            aq += xv * wqs[i*D_ + d];
            ak += xv * wks[i*D_ + d];
            av += xv * wvs[i*D_ + d];
        }
        const int tok = tok0 + t;
        const int b = tok >> 11;
        const int s = tok & (S_-1);
        const int u = s & 63;
        const int sp = (s & ~63) | (((u>>5)&1)*32 + ((u>>2)&1)*16 + ((u>>3)&3)*4 + (u&3));
        const size_t base = (size_t)(b*H_ + h)*S_;
        q[(base + s )*D_ + d] = __float2bfloat16(aq * QSCALE);
        k[(base + sp)*D_ + d] = __float2bfloat16(ak);
        v[(base + s )*D_ + d] = __float2bfloat16(av);
    }
}

// ---------------- V transpose: [B,H,S,D] -> VT [B,H,D,S] ----------------
__global__ __launch_bounds__(256) void vtrans_kernel(
    const short* __restrict__ v, short* __restrict__ vt)
{
    __shared__ short t2[D_][256];
    const int tid = threadIdx.x;
    const int bh = blockIdx.x >> 3;
    const int s0 = (blockIdx.x & 7) * 256;
    const short* src = v + ((size_t)bh*S_ + s0 + tid)*D_;
    const short8 r0 = *(const short8*)(src);
    const short8 r1 = *(const short8*)(src + 8);
    const short8 r2 = *(const short8*)(src + 16);
    const short8 r3 = *(const short8*)(src + 24);
    #pragma unroll
    for (int i = 0; i < 8; ++i) {
        t2[i     ][tid] = r0[i];
        t2[i + 8 ][tid] = r1[i];
        t2[i + 16][tid] = r2[i];
        t2[i + 24][tid] = r3[i];
    }
    __syncthreads();
    const int d = tid >> 3, j = tid & 7;
    short* dst = vt + ((size_t)(bh*D_ + d))*S_ + s0 + j*32;
    const short8* row = (const short8*)&t2[d][j*32];
    const short8 o0 = row[0], o1 = row[1], o2 = row[2], o3 = row[3];
    *(short8*)(dst     ) = o0;
    *(short8*)(dst + 8 ) = o1;
    *(short8*)(dst + 16) = o2;
    *(short8*)(dst + 24) = o3;
}

// ---------------- MFMA flash attention, LDS-staged K/V, 32 queries/wave ----------------
// Block = 4 waves x 32 queries = 128 queries sharing one key stream (32 tiles of 64).
// K LDS [64 rows][32] (64B rows), read slot = g ^ ((c>>1)&3); V LDS [32 d][64 keys]
// (128B rows), read slot = s ^ (c&7); sources inverse-swizzled (both-sides rule).
// No max-tracking: P = exp2(sc) exactly (scores tiny; masked -> 0).
__global__ __launch_bounds__(256) void attn_mfma_kernel(
    const short* __restrict__ qg, const short* __restrict__ kg,
    const short* __restrict__ vtg, const int* __restrict__ mask,
    const int* __restrict__ mflags, unsigned short* __restrict__ attn_out)
{
    __shared__ alignas(16) short lk[2][64*32];
    __shared__ alignas(16) short lv[2][32*64];

    const int tid  = threadIdx.x;
    const int lane = tid & 63;
    const int wid  = tid >> 6;
    const int c    = lane & 15;
    const int g    = lane >> 4;
    // XCD swizzle: 512 blocks, 8 XCDs -> 4 consecutive (b,h) per XCD
    const int p    = ((int)blockIdx.x & 7)*64 + ((int)blockIdx.x >> 3);
    const int bh   = p >> 4;
    const int qt   = p & 15;
    const int b    = bh >> 3;
    const int h    = bh & 7;
    const int q0   = qt*128 + wid*32;

    const short* qrow = qg + ((size_t)bh*S_ + q0 + c)*D_ + g*8;
    const short8 qfA = *(const short8*)(qrow);
    const short8 qfB = *(const short8*)(qrow + 16*D_);
    const short* kbase = kg  + (size_t)bh*S_*D_;
    const short* vbase = vtg + (size_t)bh*D_*S_;
    const int*   mrow  = mask + b*S_;

    const int fl = (lane < 32) ? mflags[b*32 + lane] : 0;
    const unsigned long long mbits = __ballot(fl != 0);

    // staging plan: waves 0,1 -> K (16-row chunks), waves 2,3 -> V (8-row chunks)
    const short* sbase; int soff0, soff1, sinc, dchunk0;
    if (wid < 2) {
        const int R0 = wid*32 + (lane >> 2);
        const int R1 = R0 + 16;
        const int s  = lane & 3;
        soff0 = R0*D_ + ((s ^ ((R0 >> 1) & 3)) << 3);
        soff1 = R1*D_ + ((s ^ ((R1 >> 1) & 3)) << 3);
        sbase = kbase; sinc = 64*D_;
        dchunk0 = wid*1024;
    } else {
        const int r0 = (wid - 2)*16 + (lane >> 3);
        const int r1 = r0 + 8;
        const int s  = lane & 7;
        soff0 = r0*S_ + ((s ^ (r0 & 7)) << 3);
        soff1 = r1*S_ + ((s ^ (r1 & 7)) << 3);
        sbase = vbase; sinc = 64;
        dchunk0 = (wid - 2)*1024;
    }

    const int kaddr = c*D_ + ((g ^ ((c >> 1) & 3)) << 3);
    const int va0   = c*64 + ((g       ^ (c & 7)) << 3);
    const int va1   = c*64 + (((g + 4) ^ (c & 7)) << 3);
    const f32x4 zero = {0.f,0.f,0.f,0.f};
    f32x4 oA0 = zero, oA1 = zero, oB0 = zero, oB1 = zero;
    float lA = 0.f, lB = 0.f;

    {   // prologue: stage tile 0 into buf 0
        short* d0 = (wid < 2 ? &lk[0][0] : &lv[0][0]) + dchunk0;
        gld16(sbase + soff0, d0);
        gld16(sbase + soff1, d0 + 512);
    }
    __syncthreads();

    int buf = 0;
    for (int t = 0; t < 32; ++t) {
        if (t < 31) {
            const short* sp = sbase + (size_t)(t + 1)*sinc;
            short* d0 = (wid < 2 ? &lk[buf ^ 1][0] : &lv[buf ^ 1][0]) + dchunk0;
            gld16(sp + soff0, d0);
            gld16(sp + soff1, d0 + 512);
        }
        const short* LK = &lk[buf][0];
        const short* LV = &lv[buf][0];
        const short8 kf0 = *(const short8*)(LK + kaddr);
        const short8 kf1 = *(const short8*)(LK + kaddr + 512);
        const short8 kf2 = *(const short8*)(LK + kaddr + 1024);
        const short8 kf3 = *(const short8*)(LK + kaddr + 1536);
        __builtin_amdgcn_s_setprio(1);
        f32x4 sA0 = __builtin_amdgcn_mfma_f32_16x16x32_bf16(kf0, qfA, zero, 0, 0, 0);
        f32x4 sA1 = __builtin_amdgcn_mfma_f32_16x16x32_bf16(kf1, qfA, zero, 0, 0, 0);
        f32x4 sA2 = __builtin_amdgcn_mfma_f32_16x16x32_bf16(kf2, qfA, zero, 0, 0, 0);
        f32x4 sA3 = __builtin_amdgcn_mfma_f32_16x16x32_bf16(kf3, qfA, zero, 0, 0, 0);
        f32x4 sB0 = __builtin_amdgcn_mfma_f32_16x16x32_bf16(kf0, qfB, zero, 0, 0, 0);
        f32x4 sB1 = __builtin_amdgcn_mfma_f32_16x16x32_bf16(kf1, qfB, zero, 0, 0, 0);
        f32x4 sB2 = __builtin_amdgcn_mfma_f32_16x16x32_bf16(kf2, qfB, zero, 0, 0, 0);
        f32x4 sB3 = __builtin_amdgcn_mfma_f32_16x16x32_bf16(kf3, qfB, zero, 0, 0, 0);
        __builtin_amdgcn_s_setprio(0);
        // mask (same keys for both q-groups); key = 64t + 32*(tt>>1) + 8g + 4*(tt&1) + r
        if ((mbits >> t) & 1ull) {
            const int kb = t*64 + 8*g;
            #pragma unroll
            for (int r = 0; r < 4; ++r) {
                if (mrow[kb      + r] == 0) { sA0[r] = -1e20f; sB0[r] = -1e20f; }
                if (mrow[kb + 4  + r] == 0) { sA1[r] = -1e20f; sB1[r] = -1e20f; }
                if (mrow[kb + 32 + r] == 0) { sA2[r] = -1e20f; sB2[r] = -1e20f; }
                if (mrow[kb + 36 + r] == 0) { sA3[r] = -1e20f; sB3[r] = -1e20f; }
            }
        }
        // P = exp2(sc)  (raw v_exp_f32)
        f32x4 pA0, pA1, pA2, pA3, pB0, pB1, pB2, pB3;
        #pragma unroll
        for (int r = 0; r < 4; ++r) {
            pA0[r] = fexp2(sA0[r]); pA1[r] = fexp2(sA1[r]);
            pA2[r] = fexp2(sA2[r]); pA3[r] = fexp2(sA3[r]);
            pB0[r] = fexp2(sB0[r]); pB1[r] = fexp2(sB1[r]);
            pB2[r] = fexp2(sB2[r]); pB3[r] = fexp2(sB3[r]);
        }
        lA += ((pA0[0]+pA0[1])+(pA0[2]+pA0[3])) + ((pA1[0]+pA1[1])+(pA1[2]+pA1[3]))
            + ((pA2[0]+pA2[1])+(pA2[2]+pA2[3])) + ((pA3[0]+pA3[1])+(pA3[2]+pA3[3]));
        lB += ((pB0[0]+pB0[1])+(pB0[2]+pB0[3])) + ((pB1[0]+pB1[1])+(pB1[2]+pB1[3]))
            + ((pB2[0]+pB2[1])+(pB2[2]+pB2[3])) + ((pB3[0]+pB3[1])+(pB3[2]+pB3[3]));
        const short8 pafA0 = __builtin_bit_cast(short8,
            (u32x4){ cvtpk_bf16(pA0[0],pA0[1]), cvtpk_bf16(pA0[2],pA0[3]),
                     cvtpk_bf16(pA1[0],pA1[1]), cvtpk_bf16(pA1[2],pA1[3]) });
        const short8 pafA1 = __builtin_bit_cast(short8,
            (u32x4){ cvtpk_bf16(pA2[0],pA2[1]), cvtpk_bf16(pA2[2],pA2[3]),
                     cvtpk_bf16(pA3[0],pA3[1]), cvtpk_bf16(pA3[2],pA3[3]) });
        const short8 pafB0 = __builtin_bit_cast(short8,
            (u32x4){ cvtpk_bf16(pB0[0],pB0[1]), cvtpk_bf16(pB0[2],pB0[3]),
                     cvtpk_bf16(pB1[0],pB1[1]), cvtpk_bf16(pB1[2],pB1[3]) });
        const short8 pafB1 = __builtin_bit_cast(short8,
            (u32x4){ cvtpk_bf16(pB2[0],pB2[1]), cvtpk_bf16(pB2[2],pB2[3]),
                     cvtpk_bf16(pB3[0],pB3[1]), cvtpk_bf16(pB3[2],pB3[3]) });
        const short8 vf0 = *(const short8*)(LV + va0);
        const short8 vf1 = *(const short8*)(LV + va1);
        const short8 vf2 = *(const short8*)(LV + va0 + 1024);
        const short8 vf3 = *(const short8*)(LV + va1 + 1024);
        __builtin_amdgcn_s_setprio(1);
        oA0 = __builtin_amdgcn_mfma_f32_16x16x32_bf16(vf0, pafA0, oA0, 0, 0, 0);
        oA0 = __builtin_amdgcn_mfma_f32_16x16x32_bf16(vf1, pafA1, oA0, 0, 0, 0);
        oA1 = __builtin_amdgcn_mfma_f32_16x16x32_bf16(vf2, pafA0, oA1, 0, 0, 0);
        oA1 = __builtin_amdgcn_mfma_f32_16x16x32_bf16(vf3, pafA1, oA1, 0, 0, 0);
        oB0 = __builtin_amdgcn_mfma_f32_16x16x32_bf16(vf0, pafB0, oB0, 0, 0, 0);
        oB0 = __builtin_amdgcn_mfma_f32_16x16x32_bf16(vf1, pafB1, oB0, 0, 0, 0);
        oB1 = __builtin_amdgcn_mfma_f32_16x16x32_bf16(vf2, pafB0, oB1, 0, 0, 0);
        oB1 = __builtin_amdgcn_mfma_f32_16x16x32_bf16(vf3, pafB1, oB1, 0, 0, 0);
        __builtin_amdgcn_s_setprio(0);
        __syncthreads();
        buf ^= 1;
    }
    lA += __shfl_xor(lA, 16); lA += __shfl_xor(lA, 32);
    lB += __shfl_xor(lB, 16); lB += __shfl_xor(lB, 32);
    const float invA = 1.0f / lA, invB = 1.0f / lB;
    unsigned short* orowA = attn_out + ((size_t)b*S_ + q0 + c)*E_ + h*D_ + g*4;
    unsigned short* orowB = orowA + (size_t)16*E_;
    uint2 a0, a1, b0, b1;
    a0.x = cvtpk_bf16(oA0[0]*invA, oA0[1]*invA); a0.y = cvtpk_bf16(oA0[2]*invA, oA0[3]*invA);
    a1.x = cvtpk_bf16(oA1[0]*invA, oA1[1]*invA); a1.y = cvtpk_bf16(oA1[2]*invA, oA1[3]*invA);
    b0.x = cvtpk_bf16(oB0[0]*invB, oB0[1]*invB); b0.y = cvtpk_bf16(oB0[2]*invB, oB0[3]*invB);
    b1.x = cvtpk_bf16(oB1[0]*invB, oB1[1]*invB); b1.y = cvtpk_bf16(oB1[2]*invB, oB1[3]*invB);
    *(uint2*)(orowA)      = a0;
    *(uint2*)(orowA + 16) = a1;
    *(uint2*)(orowB)      = b0;
    *(uint2*)(orowB + 16) = b1;
}

// ---------------- bf16 MFMA GEMM: C[M,N] = op(A[M,K] @ WT[N,K]^T + bias) ----------------
// BK=64, 256 thr = 4 waves (2x2). global_load_lds + XOR slot swizzle.
template<int BM, int BN, int RELU, int RESID, int WF32, int WBF16>
__global__ __launch_bounds__(256) void mgemm_kernel(
    const short* __restrict__ A, const short* __restrict__ WT,
    const float* __restrict__ bias, const float* __restrict__ R,
    float* __restrict__ C32, unsigned short* __restrict__ Cb,
    int M, int N, int K)
{
    constexpr int FR = BM / 32;
    constexpr int FC = BN / 32;
    __shared__ alignas(16) short As[BM*64];
    __shared__ alignas(16) short Bs[BN*64];
    const int t = threadIdx.x, w = t >> 6, lane = t & 63;
    const int col = lane & 15, grp = lane >> 4;
    const int wm = w >> 1, wn = w & 1;
    const int bm = blockIdx.y, bn = blockIdx.x;
    const int arow = t >> 3, ac = t & 7;

    f32x4 acc[FR][FC];
    #pragma unroll
    for (int i = 0; i < FR; ++i)
        #pragma unroll
        for (int j = 0; j < FC; ++j) acc[i][j] = (f32x4){0.f,0.f,0.f,0.f};

    for (int kb = 0; kb < K; kb += 64) {
        #pragma unroll
        for (int b2 = 0; b2 < BM/32; ++b2) {
            const int row = b2*32 + arow;
            gld16(A + (size_t)(bm*BM + row)*K + kb + ((ac ^ (row & 7)) << 3),
                  As + b2*2048 + w*512);
        }
        #pragma unroll
        for (int b2 = 0; b2 < BN/32; ++b2) {
            const int row = b2*32 + arow;
            gld16(WT + (size_t)(bn*BN + row)*K + kb + ((ac ^ (row & 7)) << 3),
                  Bs + b2*2048 + w*512);
        }
        __syncthreads();
        #pragma unroll
        for (int s = 0; s < 2; ++s) {
            short8 af[FR], bf_[FC];
            #pragma unroll
            for (int fr = 0; fr < FR; ++fr)
                af[fr] = lds_frag(As, wm*(BM/2) + fr*16 + col, s*4 + grp);
            #pragma unroll
            for (int fc = 0; fc < FC; ++fc)
                bf_[fc] = lds_frag(Bs, wn*(BN/2) + fc*16 + col, s*4 + grp);
            #pragma unroll
            for (int fr = 0; fr < FR; ++fr)
                #pragma unroll
                for (int fc = 0; fc < FC; ++fc)
                    acc[fr][fc] = __builtin_amdgcn_mfma_f32_16x16x32_bf16(af[fr], bf_[fc], acc[fr][fc], 0, 0, 0);
        }
        __syncthreads();
    }

    #pragma unroll
    for (int fc = 0; fc < FC; ++fc) {
        const int n = bn*BN + wn*(BN/2) + fc*16 + col;
        const float bs = bias[n];
        #pragma unroll
        for (int fr = 0; fr < FR; ++fr) {
            #pragma unroll
            for (int reg = 0; reg < 4; ++reg) {
                const int m = bm*BM + wm*(BM/2) + fr*16 + grp*4 + reg;
                float v = acc[fr][fc][reg] + bs;
                if (RELU) v = fmaxf(v, 0.f);
                if (RESID) v += R[(size_t)m*N + n];
                if (WF32) C32[(size_t)m*N + n] = v;
                if (WBF16) Cb[(size_t)m*N + n] = round_bf16(v);
            }
        }
    }
}

// ---------------- series decomposition over E (window 25, edge pad) ----------------
template<int WF32, int WBF16>
__global__ __launch_bounds__(256) void decomp_kernel(
    const float* __restrict__ in, float* __restrict__ o32, unsigned short* __restrict__ ob)
{
    __shared__ float r[E_];
    const int row = blockIdx.x, e = threadIdx.x;
    const float xv = in[(size_t)row*E_ + e];
    r[e] = xv;
    __syncthreads();
    float sum = 0.f;
    #pragma unroll
    for (int j = -12; j <= 12; ++j) {
        int idx = e + j;
        idx = idx < 0 ? 0 : (idx > E_-1 ? E_-1 : idx);
        sum += r[idx];
    }
    const float res = xv - sum * (1.0f/25.0f);
    if (WF32) o32[(size_t)row*E_ + e] = res;
    if (WBF16) ob[(size_t)row*E_ + e] = round_bf16(res);
}

extern "C" void kernel_launch(void* const* d_in, const int* in_sizes, int n_in,
                              void* d_out, int out_size, void* d_ws, size_t ws_size,
                              hipStream_t stream) {
    const float* x     = (const float*)d_in[0];
    const int*   mask  = (const int*)  d_in[1];
    const float* wq    = (const float*)d_in[2];
    const float* wk    = (const float*)d_in[3];
    const float* wv    = (const float*)d_in[4];
    const float* w_out = (const float*)d_in[5];
    const float* b_out = (const float*)d_in[6];
    const float* ff_w1 = (const float*)d_in[7];
    const float* ff_b1 = (const float*)d_in[8];
    const float* ff_w2 = (const float*)d_in[9];
    const float* ff_b2 = (const float*)d_in[10];
    const float* pr_w1 = (const float*)d_in[11];
    const float* pr_b1 = (const float*)d_in[12];
    const float* pr_w2 = (const float*)d_in[13];
    const float* pr_b2 = (const float*)d_in[14];
    float* out = (float*)d_out;

    char* ws = (char*)d_ws;
    const size_t MB = 1024ull*1024ull;
    const size_t KB = 1024ull;
    bf16*  qb    = (bf16*)(ws + 0*MB);
    bf16*  kbf   = (bf16*)(ws + 4*MB);
    bf16*  vbf   = (bf16*)(ws + 8*MB);
    bf16*  vtb   = (bf16*)(ws + 12*MB);
    unsigned short* attnb = (unsigned short*)(ws + 16*MB);   // 4MB bf16
    float* x1    = (float*)(ws + 20*MB);                     // 8MB
    float* y32   = (float*)(ws + 28*MB);                     // 8MB
    unsigned short* yb  = (unsigned short*)(ws + 36*MB);     // 4MB
    unsigned short* h1  = (unsigned short*)(ws + 0*MB);      // 16MB (qkv dead)
    float* s32   = (float*)(ws + 20*MB);                     // 8MB (x1 dead)
    unsigned short* s2b = (unsigned short*)(ws + 16*MB);     // 4MB (attnb dead)
    unsigned short* h2  = (unsigned short*)(ws + 0*MB);      // 16MB (h1 dead)
    unsigned short* woT = (unsigned short*)(ws + 40*MB);                // 128KB
    unsigned short* f1T = (unsigned short*)(ws + 40*MB + 128*KB);       // 512KB
    unsigned short* f2T = (unsigned short*)(ws + 40*MB + 640*KB);       // 512KB
    unsigned short* p1T = (unsigned short*)(ws + 40*MB + 1152*KB);      // 512KB
    unsigned short* p2T = (unsigned short*)(ws + 40*MB + 1664*KB);      // 512KB
    int*            mfl = (int*)           (ws + 40*MB + 2176*KB);      // 512B

    // 0. fused weight convert+transpose + mask tile scan
    prep_kernel<<<1089, 256, 0, stream>>>(w_out, ff_w1, ff_w2, pr_w1, pr_w2,
                                          woT, f1T, f2T, p1T, p2T, mask, mfl);
    // 1. QKV (bf16, Q pre-scaled, K row-permuted) + V transpose
    qkv_kernel<<<NTOK/16, 256, 0, stream>>>(x, wq, wk, wv, qb, kbf, vbf);
    vtrans_kernel<<<B_*H_*(S_/256), 256, 0, stream>>>((const short*)vbf, (short*)vtb);
    // 2. MFMA flash attention (LDS-staged K/V, 128 q per block) -> bf16
    attn_mfma_kernel<<<B_*H_*S_/128, 256, 0, stream>>>(
        (const short*)qb, (const short*)kbf, (const short*)vtb, mask, mfl, attnb);
    // 3. out-proj + residual: x1 = x + attn @ w_out + b_out   (fp32 out)
    mgemm_kernel<64,64,0,1,1,0><<<dim3(E_/64, NTOK/64), 256, 0, stream>>>(
        (const short*)attnb, (const short*)woT, b_out, x, x1, nullptr, NTOK, E_, E_);
    // 4. decomposition 1: y (fp32 + bf16)
    decomp_kernel<1,1><<<NTOK, 256, 0, stream>>>(x1, y32, yb);
    // 5. FFN
    mgemm_kernel<128,128,1,0,0,1><<<dim3(FF_/128, NTOK/128), 256, 0, stream>>>(
        (const short*)yb, (const short*)f1T, ff_b1, nullptr, nullptr, h1, NTOK, FF_, E_);
    mgemm_kernel<64,64,0,1,1,0><<<dim3(E_/64, NTOK/64), 256, 0, stream>>>(
        (const short*)h1, (const short*)f2T, ff_b2, y32, s32, nullptr, NTOK, E_, FF_);
    // 6. decomposition 2: s2 (bf16 only)
    decomp_kernel<0,1><<<NTOK, 256, 0, stream>>>(s32, nullptr, s2b);
    // 7. projection FFN
    mgemm_kernel<128,128,1,0,0,1><<<dim3(FF_/128, NTOK/128), 256, 0, stream>>>(
        (const short*)s2b, (const short*)p1T, pr_b1, nullptr, nullptr, h2, NTOK, FF_, E_);
    mgemm_kernel<64,64,0,0,1,0><<<dim3(E_/64, NTOK/64), 256, 0, stream>>>(
        (const short*)h2, (const short*)p2T, pr_b2, nullptr, out, nullptr, NTOK, E_, FF_);
}

// Round 8
// 125.321 us; speedup vs baseline: 2.1135x; 1.0320x over previous
//
#include <hip/hip_runtime.h>
#include <hip/hip_bf16.h>
#include <math.h>

#define B_   4
#define S_   2048
#define E_   256
#define H_   8
#define D_   32
#define FF_  1024
#define NTOK (B_*S_)   // 8192

typedef __attribute__((ext_vector_type(8))) short short8;
typedef __attribute__((ext_vector_type(4))) float f32x4;
typedef __attribute__((ext_vector_type(4))) unsigned u32x4;
typedef __hip_bfloat16 bf16;

#define QSCALE 0.09016844005556021f   // (1/16) * log2(e)

__device__ __forceinline__ unsigned short round_bf16(float a) {
    unsigned ua = __builtin_bit_cast(unsigned, a);
    return (unsigned short)((ua + 0x7fffu + ((ua >> 16) & 1u)) >> 16);
}
__device__ __forceinline__ unsigned cvtpk_bf16(float lo, float hi) {
    unsigned r;
    asm("v_cvt_pk_bf16_f32 %0, %1, %2" : "=v"(r) : "v"(lo), "v"(hi));
    return r;
}
__device__ __forceinline__ float fexp2(float x) {
    float r;
    asm("v_exp_f32 %0, %1" : "=v"(r) : "v"(x));
    return r;
}
__device__ __forceinline__ void gld16(const short* g, short* l) {
    __builtin_amdgcn_global_load_lds(
        (const __attribute__((address_space(1))) unsigned int*)g,
        (__attribute__((address_space(3))) unsigned int*)l, 16, 0, 0);
}
// GEMM LDS tile: row stride 64 shorts (128B); 16B slot index = c16 ^ (row&7)
__device__ __forceinline__ short8 lds_frag(const short* base, int r, int c16) {
    return *(const short8*)(base + r*64 + (((c16) ^ (r & 7)) << 3));
}

// ---------------- fused QKV + weight-prep + maskscan ----------------
// blocks 0..511: QKV projection. blocks 512..1599: weight conv/transpose.
// block 1600: maskscan.
// Q pre-scaled by QSCALE. K stored PERMUTED within each 64-row tile:
// token u (=s&63) -> row 32*((u>>5)&1) + 16*((u>>2)&1) + 4*((u>>3)&3) + (u&3),
// so reading row s yields key perm(s)=32c+8g+4a+b (s=32c+16a+4g+b).
__global__ __launch_bounds__(256) void qkv_prep_kernel(
    const float* __restrict__ x,
    const float* __restrict__ wq, const float* __restrict__ wk, const float* __restrict__ wv,
    bf16* __restrict__ q, bf16* __restrict__ k, bf16* __restrict__ v,
    const float* __restrict__ w_out, const float* __restrict__ ff_w1,
    const float* __restrict__ ff_w2, const float* __restrict__ pr_w1,
    const float* __restrict__ pr_w2,
    unsigned short* __restrict__ woT, unsigned short* __restrict__ f1T,
    unsigned short* __restrict__ f2T, unsigned short* __restrict__ p1T,
    unsigned short* __restrict__ p2T,
    const int* __restrict__ mask, int* __restrict__ mflags)
{
    const int bid = blockIdx.x;
    if (bid >= 512) {
        const int pb = bid - 512;
        if (pb >= 1088) {   // maskscan
            const int t = threadIdx.x;
            if (t < 128) {
                const int* p = mask + (t >> 5)*S_ + (t & 31)*64;
                int any0 = 0;
                #pragma unroll
                for (int i = 0; i < 16; ++i) {
                    const int4 vv = *(const int4*)(p + i*4);
                    if (!(vv.x && vv.y && vv.z && vv.w)) any0 = 1;
                }
                mflags[t] = any0;
            }
            return;
        }
        const float* w; unsigned short* wt; int K, N, idx;
        if (pb < 64)       { w = w_out; wt = woT; K = E_;  N = E_;  idx = pb; }
        else if (pb < 320) { w = ff_w1; wt = f1T; K = E_;  N = FF_; idx = pb - 64; }
        else if (pb < 576) { w = ff_w2; wt = f2T; K = FF_; N = E_;  idx = pb - 320; }
        else if (pb < 832) { w = pr_w1; wt = p1T; K = E_;  N = FF_; idx = pb - 576; }
        else               { w = pr_w2; wt = p2T; K = FF_; N = E_;  idx = pb - 832; }
        const int nb = N/32;
        const int n0 = (idx % nb)*32, k0 = (idx / nb)*32;
        __shared__ float tile[32][33];
        const int c = threadIdx.x & 31, r0 = threadIdx.x >> 5;
        #pragma unroll
        for (int i = 0; i < 4; ++i)
            tile[r0 + 8*i][c] = w[(size_t)(k0 + r0 + 8*i)*N + n0 + c];
        __syncthreads();
        #pragma unroll
        for (int i = 0; i < 4; ++i)
            wt[(size_t)(n0 + r0 + 8*i)*K + k0 + c] = round_bf16(tile[c][r0 + 8*i]);
        return;
    }
    // ---- QKV ----
    __shared__ float wqs[D_*D_], wks[D_*D_], wvs[D_*D_];
    __shared__ float xs[16][E_];
    const int tid = threadIdx.x;
    for (int i = tid; i < D_*D_; i += 256) {
        wqs[i] = wq[i]; wks[i] = wk[i]; wvs[i] = wv[i];
    }
    const int tok0 = bid * 16;
    #pragma unroll
    for (int i = 0; i < 16; ++i)
        xs[i][tid] = x[(size_t)(tok0 + i)*E_ + tid];
    __syncthreads();
    const int h = tid >> 5, d = tid & 31;
    for (int t = 0; t < 16; ++t) {
        float aq = 0.f, ak = 0.f, av = 0.f;
        #pragma unroll
        for (int i = 0; i < D_; ++i) {
            const float xv = xs[t][h*D_ + i];
            aq += xv * wqs[i*D_ + d];
            ak += xv * wks[i*D_ + d];
            av += xv * wvs[i*D_ + d];
        }
        const int tok = tok0 + t;
        const int b = tok >> 11;
        const int s = tok & (S_-1);
        const int u = s & 63;
        const int sp = (s & ~63) | (((u>>5)&1)*32 + ((u>>2)&1)*16 + ((u>>3)&3)*4 + (u&3));
        const size_t base = (size_t)(b*H_ + h)*S_;
        q[(base + s )*D_ + d] = __float2bfloat16(aq * QSCALE);
        k[(base + sp)*D_ + d] = __float2bfloat16(ak);
        v[(base + s )*D_ + d] = __float2bfloat16(av);
    }
}

// ---------------- V transpose: [B,H,S,D] -> VT [B,H,D,S] ----------------
__global__ __launch_bounds__(256) void vtrans_kernel(
    const short* __restrict__ v, short* __restrict__ vt)
{
    __shared__ short t2[D_][256];
    const int tid = threadIdx.x;
    const int bh = blockIdx.x >> 3;
    const int s0 = (blockIdx.x & 7) * 256;
    const short* src = v + ((size_t)bh*S_ + s0 + tid)*D_;
    const short8 r0 = *(const short8*)(src);
    const short8 r1 = *(const short8*)(src + 8);
    const short8 r2 = *(const short8*)(src + 16);
    const short8 r3 = *(const short8*)(src + 24);
    #pragma unroll
    for (int i = 0; i < 8; ++i) {
        t2[i     ][tid] = r0[i];
        t2[i + 8 ][tid] = r1[i];
        t2[i + 16][tid] = r2[i];
        t2[i + 24][tid] = r3[i];
    }
    __syncthreads();
    const int d = tid >> 3, j = tid & 7;
    short* dst = vt + ((size_t)(bh*D_ + d))*S_ + s0 + j*32;
    const short8* row = (const short8*)&t2[d][j*32];
    const short8 o0 = row[0], o1 = row[1], o2 = row[2], o3 = row[3];
    *(short8*)(dst     ) = o0;
    *(short8*)(dst + 8 ) = o1;
    *(short8*)(dst + 16) = o2;
    *(short8*)(dst + 24) = o3;
}

// ---------------- MFMA flash attention, LDS-staged K/V, 32 queries/wave ----------------
// Block = 4 waves x 32 queries = 128 queries sharing one key stream (32 tiles of 64).
// K LDS [64 rows][32] (64B rows), read slot = g ^ ((c>>1)&3); V LDS [32 d][64 keys]
// (128B rows), read slot = s ^ (c&7); sources inverse-swizzled (both-sides rule).
// No max-tracking: P = exp2(sc) exactly. Row-sum l via MFMA ones-trick.
__global__ __launch_bounds__(256) void attn_mfma_kernel(
    const short* __restrict__ qg, const short* __restrict__ kg,
    const short* __restrict__ vtg, const int* __restrict__ mask,
    const int* __restrict__ mflags, unsigned short* __restrict__ attn_out)
{
    __shared__ alignas(16) short lk[2][64*32];
    __shared__ alignas(16) short lv[2][32*64];

    const int tid  = threadIdx.x;
    const int lane = tid & 63;
    const int wid  = tid >> 6;
    const int c    = lane & 15;
    const int g    = lane >> 4;
    // XCD swizzle: 512 blocks, 8 XCDs -> 4 consecutive (b,h) per XCD
    const int p    = ((int)blockIdx.x & 7)*64 + ((int)blockIdx.x >> 3);
    const int bh   = p >> 4;
    const int qt   = p & 15;
    const int b    = bh >> 3;
    const int h    = bh & 7;
    const int q0   = qt*128 + wid*32;

    const short* qrow = qg + ((size_t)bh*S_ + q0 + c)*D_ + g*8;
    const short8 qfA = *(const short8*)(qrow);
    const short8 qfB = *(const short8*)(qrow + 16*D_);
    const short* kbase = kg  + (size_t)bh*S_*D_;
    const short* vbase = vtg + (size_t)bh*D_*S_;
    const int*   mrow  = mask + b*S_;

    const int fl = (lane < 32) ? mflags[b*32 + lane] : 0;
    const unsigned long long mbits = __ballot(fl != 0);

    // staging plan: waves 0,1 -> K (16-row chunks), waves 2,3 -> V (8-row chunks)
    const short* sbase; int soff0, soff1, sinc, dchunk0;
    if (wid < 2) {
        const int R0 = wid*32 + (lane >> 2);
        const int R1 = R0 + 16;
        const int s  = lane & 3;
        soff0 = R0*D_ + ((s ^ ((R0 >> 1) & 3)) << 3);
        soff1 = R1*D_ + ((s ^ ((R1 >> 1) & 3)) << 3);
        sbase = kbase; sinc = 64*D_;
        dchunk0 = wid*1024;
    } else {
        const int r0 = (wid - 2)*16 + (lane >> 3);
        const int r1 = r0 + 8;
        const int s  = lane & 7;
        soff0 = r0*S_ + ((s ^ (r0 & 7)) << 3);
        soff1 = r1*S_ + ((s ^ (r1 & 7)) << 3);
        sbase = vbase; sinc = 64;
        dchunk0 = (wid - 2)*1024;
    }

    const int kaddr = c*D_ + ((g ^ ((c >> 1) & 3)) << 3);
    const int va0   = c*64 + ((g       ^ (c & 7)) << 3);
    const int va1   = c*64 + (((g + 4) ^ (c & 7)) << 3);
    const f32x4 zero = {0.f,0.f,0.f,0.f};
    const short8 ones = { (short)0x3F80, (short)0x3F80, (short)0x3F80, (short)0x3F80,
                          (short)0x3F80, (short)0x3F80, (short)0x3F80, (short)0x3F80 };
    f32x4 oA0 = zero, oA1 = zero, oB0 = zero, oB1 = zero;
    f32x4 lAacc = zero, lBacc = zero;

    {   // prologue: stage tile 0 into buf 0
        short* d0 = (wid < 2 ? &lk[0][0] : &lv[0][0]) + dchunk0;
        gld16(sbase + soff0, d0);
        gld16(sbase + soff1, d0 + 512);
    }
    __syncthreads();

    int buf = 0;
    for (int t = 0; t < 32; ++t) {
        if (t < 31) {
            const short* sp = sbase + (size_t)(t + 1)*sinc;
            short* d0 = (wid < 2 ? &lk[buf ^ 1][0] : &lv[buf ^ 1][0]) + dchunk0;
            gld16(sp + soff0, d0);
            gld16(sp + soff1, d0 + 512);
        }
        const short* LK = &lk[buf][0];
        const short* LV = &lv[buf][0];
        const short8 kf0 = *(const short8*)(LK + kaddr);
        const short8 kf1 = *(const short8*)(LK + kaddr + 512);
        const short8 kf2 = *(const short8*)(LK + kaddr + 1024);
        const short8 kf3 = *(const short8*)(LK + kaddr + 1536);
        __builtin_amdgcn_s_setprio(1);
        f32x4 sA0 = __builtin_amdgcn_mfma_f32_16x16x32_bf16(kf0, qfA, zero, 0, 0, 0);
        f32x4 sA1 = __builtin_amdgcn_mfma_f32_16x16x32_bf16(kf1, qfA, zero, 0, 0, 0);
        f32x4 sA2 = __builtin_amdgcn_mfma_f32_16x16x32_bf16(kf2, qfA, zero, 0, 0, 0);
        f32x4 sA3 = __builtin_amdgcn_mfma_f32_16x16x32_bf16(kf3, qfA, zero, 0, 0, 0);
        f32x4 sB0 = __builtin_amdgcn_mfma_f32_16x16x32_bf16(kf0, qfB, zero, 0, 0, 0);
        f32x4 sB1 = __builtin_amdgcn_mfma_f32_16x16x32_bf16(kf1, qfB, zero, 0, 0, 0);
        f32x4 sB2 = __builtin_amdgcn_mfma_f32_16x16x32_bf16(kf2, qfB, zero, 0, 0, 0);
        f32x4 sB3 = __builtin_amdgcn_mfma_f32_16x16x32_bf16(kf3, qfB, zero, 0, 0, 0);
        __builtin_amdgcn_s_setprio(0);
        // mask (same keys for both q-groups); key = 64t + 32*(tt>>1) + 8g + 4*(tt&1) + r
        if ((mbits >> t) & 1ull) {
            const int kb = t*64 + 8*g;
            #pragma unroll
            for (int r = 0; r < 4; ++r) {
                if (mrow[kb      + r] == 0) { sA0[r] = -1e20f; sB0[r] = -1e20f; }
                if (mrow[kb + 4  + r] == 0) { sA1[r] = -1e20f; sB1[r] = -1e20f; }
                if (mrow[kb + 32 + r] == 0) { sA2[r] = -1e20f; sB2[r] = -1e20f; }
                if (mrow[kb + 36 + r] == 0) { sA3[r] = -1e20f; sB3[r] = -1e20f; }
            }
        }
        // P = exp2(sc)  (raw v_exp_f32)
        f32x4 pA0, pA1, pA2, pA3, pB0, pB1, pB2, pB3;
        #pragma unroll
        for (int r = 0; r < 4; ++r) {
            pA0[r] = fexp2(sA0[r]); pA1[r] = fexp2(sA1[r]);
            pA2[r] = fexp2(sA2[r]); pA3[r] = fexp2(sA3[r]);
            pB0[r] = fexp2(sB0[r]); pB1[r] = fexp2(sB1[r]);
            pB2[r] = fexp2(sB2[r]); pB3[r] = fexp2(sB3[r]);
        }
        const short8 pafA0 = __builtin_bit_cast(short8,
            (u32x4){ cvtpk_bf16(pA0[0],pA0[1]), cvtpk_bf16(pA0[2],pA0[3]),
                     cvtpk_bf16(pA1[0],pA1[1]), cvtpk_bf16(pA1[2],pA1[3]) });
        const short8 pafA1 = __builtin_bit_cast(short8,
            (u32x4){ cvtpk_bf16(pA2[0],pA2[1]), cvtpk_bf16(pA2[2],pA2[3]),
                     cvtpk_bf16(pA3[0],pA3[1]), cvtpk_bf16(pA3[2],pA3[3]) });
        const short8 pafB0 = __builtin_bit_cast(short8,
            (u32x4){ cvtpk_bf16(pB0[0],pB0[1]), cvtpk_bf16(pB0[2],pB0[3]),
                     cvtpk_bf16(pB1[0],pB1[1]), cvtpk_bf16(pB1[2],pB1[3]) });
        const short8 pafB1 = __builtin_bit_cast(short8,
            (u32x4){ cvtpk_bf16(pB2[0],pB2[1]), cvtpk_bf16(pB2[2],pB2[3]),
                     cvtpk_bf16(pB3[0],pB3[1]), cvtpk_bf16(pB3[2],pB3[3]) });
        const short8 vf0 = *(const short8*)(LV + va0);
        const short8 vf1 = *(const short8*)(LV + va1);
        const short8 vf2 = *(const short8*)(LV + va0 + 1024);
        const short8 vf3 = *(const short8*)(LV + va1 + 1024);
        __builtin_amdgcn_s_setprio(1);
        oA0 = __builtin_amdgcn_mfma_f32_16x16x32_bf16(vf0, pafA0, oA0, 0, 0, 0);
        oA0 = __builtin_amdgcn_mfma_f32_16x16x32_bf16(vf1, pafA1, oA0, 0, 0, 0);
        oA1 = __builtin_amdgcn_mfma_f32_16x16x32_bf16(vf2, pafA0, oA1, 0, 0, 0);
        oA1 = __builtin_amdgcn_mfma_f32_16x16x32_bf16(vf3, pafA1, oA1, 0, 0, 0);
        oB0 = __builtin_amdgcn_mfma_f32_16x16x32_bf16(vf0, pafB0, oB0, 0, 0, 0);
        oB0 = __builtin_amdgcn_mfma_f32_16x16x32_bf16(vf1, pafB1, oB0, 0, 0, 0);
        oB1 = __builtin_amdgcn_mfma_f32_16x16x32_bf16(vf2, pafB0, oB1, 0, 0, 0);
        oB1 = __builtin_amdgcn_mfma_f32_16x16x32_bf16(vf3, pafB1, oB1, 0, 0, 0);
        // row-sum l via ones A-fragment: lacc[r][q] += sum_k P[k][q]
        lAacc = __builtin_amdgcn_mfma_f32_16x16x32_bf16(ones, pafA0, lAacc, 0, 0, 0);
        lAacc = __builtin_amdgcn_mfma_f32_16x16x32_bf16(ones, pafA1, lAacc, 0, 0, 0);
        lBacc = __builtin_amdgcn_mfma_f32_16x16x32_bf16(ones, pafB0, lBacc, 0, 0, 0);
        lBacc = __builtin_amdgcn_mfma_f32_16x16x32_bf16(ones, pafB1, lBacc, 0, 0, 0);
        __builtin_amdgcn_s_setprio(0);
        __syncthreads();
        buf ^= 1;
    }
    const float invA = 1.0f / lAacc[0], invB = 1.0f / lBacc[0];
    unsigned short* orowA = attn_out + ((size_t)b*S_ + q0 + c)*E_ + h*D_ + g*4;
    unsigned short* orowB = orowA + (size_t)16*E_;
    uint2 a0, a1, b0, b1;
    a0.x = cvtpk_bf16(oA0[0]*invA, oA0[1]*invA); a0.y = cvtpk_bf16(oA0[2]*invA, oA0[3]*invA);
    a1.x = cvtpk_bf16(oA1[0]*invA, oA1[1]*invA); a1.y = cvtpk_bf16(oA1[2]*invA, oA1[3]*invA);
    b0.x = cvtpk_bf16(oB0[0]*invB, oB0[1]*invB); b0.y = cvtpk_bf16(oB0[2]*invB, oB0[3]*invB);
    b1.x = cvtpk_bf16(oB1[0]*invB, oB1[1]*invB); b1.y = cvtpk_bf16(oB1[2]*invB, oB1[3]*invB);
    *(uint2*)(orowA)      = a0;
    *(uint2*)(orowA + 16) = a1;
    *(uint2*)(orowB)      = b0;
    *(uint2*)(orowB + 16) = b1;
}

// ---------------- bf16 MFMA GEMM: C[M,N] = op(A[M,K] @ WT[N,K]^T + bias) ----------------
// BK=64, 256 thr = 4 waves (2x2). global_load_lds + XOR slot swizzle.
// 1-D grid with XCD-chunk swizzle (nwg must be divisible by 8).
template<int BM, int BN, int RELU, int RESID, int WF32, int WBF16>
__global__ __launch_bounds__(256) void mgemm_kernel(
    const short* __restrict__ A, const short* __restrict__ WT,
    const float* __restrict__ bias, const float* __restrict__ R,
    float* __restrict__ C32, unsigned short* __restrict__ Cb,
    int M, int N, int K)
{
    constexpr int FR = BM / 32;
    constexpr int FC = BN / 32;
    __shared__ alignas(16) short As[BM*64];
    __shared__ alignas(16) short Bs[BN*64];
    const int t = threadIdx.x, w = t >> 6, lane = t & 63;
    const int col = lane & 15, grp = lane >> 4;
    const int wm = w >> 1, wn = w & 1;
    const int gx = N / BN;
    const int nwg = gridDim.x;
    const int lin = ((int)blockIdx.x & 7)*(nwg >> 3) + ((int)blockIdx.x >> 3);
    const int bm = lin / gx, bn = lin % gx;
    const int arow = t >> 3, ac = t & 7;

    f32x4 acc[FR][FC];
    #pragma unroll
    for (int i = 0; i < FR; ++i)
        #pragma unroll
        for (int j = 0; j < FC; ++j) acc[i][j] = (f32x4){0.f,0.f,0.f,0.f};

    for (int kb = 0; kb < K; kb += 64) {
        #pragma unroll
        for (int b2 = 0; b2 < BM/32; ++b2) {
            const int row = b2*32 + arow;
            gld16(A + (size_t)(bm*BM + row)*K + kb + ((ac ^ (row & 7)) << 3),
                  As + b2*2048 + w*512);
        }
        #pragma unroll
        for (int b2 = 0; b2 < BN/32; ++b2) {
            const int row = b2*32 + arow;
            gld16(WT + (size_t)(bn*BN + row)*K + kb + ((ac ^ (row & 7)) << 3),
                  Bs + b2*2048 + w*512);
        }
        __syncthreads();
        #pragma unroll
        for (int s = 0; s < 2; ++s) {
            short8 af[FR], bf_[FC];
            #pragma unroll
            for (int fr = 0; fr < FR; ++fr)
                af[fr] = lds_frag(As, wm*(BM/2) + fr*16 + col, s*4 + grp);
            #pragma unroll
            for (int fc = 0; fc < FC; ++fc)
                bf_[fc] = lds_frag(Bs, wn*(BN/2) + fc*16 + col, s*4 + grp);
            #pragma unroll
            for (int fr = 0; fr < FR; ++fr)
                #pragma unroll
                for (int fc = 0; fc < FC; ++fc)
                    acc[fr][fc] = __builtin_amdgcn_mfma_f32_16x16x32_bf16(af[fr], bf_[fc], acc[fr][fc], 0, 0, 0);
        }
        __syncthreads();
    }

    #pragma unroll
    for (int fc = 0; fc < FC; ++fc) {
        const int n = bn*BN + wn*(BN/2) + fc*16 + col;
        const float bs = bias[n];
        #pragma unroll
        for (int fr = 0; fr < FR; ++fr) {
            #pragma unroll
            for (int reg = 0; reg < 4; ++reg) {
                const int m = bm*BM + wm*(BM/2) + fr*16 + grp*4 + reg;
                float v = acc[fr][fc][reg] + bs;
                if (RELU) v = fmaxf(v, 0.f);
                if (RESID) v += R[(size_t)m*N + n];
                if (WF32) C32[(size_t)m*N + n] = v;
                if (WBF16) Cb[(size_t)m*N + n] = round_bf16(v);
            }
        }
    }
}

// ---------------- series decomposition over E (window 25, edge pad) ----------------
template<int WF32, int WBF16>
__global__ __launch_bounds__(256) void decomp_kernel(
    const float* __restrict__ in, float* __restrict__ o32, unsigned short* __restrict__ ob)
{
    __shared__ float r[E_];
    const int row = blockIdx.x, e = threadIdx.x;
    const float xv = in[(size_t)row*E_ + e];
    r[e] = xv;
    __syncthreads();
    float sum = 0.f;
    #pragma unroll
    for (int j = -12; j <= 12; ++j) {
        int idx = e + j;
        idx = idx < 0 ? 0 : (idx > E_-1 ? E_-1 : idx);
        sum += r[idx];
    }
    const float res = xv - sum * (1.0f/25.0f);
    if (WF32) o32[(size_t)row*E_ + e] = res;
    if (WBF16) ob[(size_t)row*E_ + e] = round_bf16(res);
}

extern "C" void kernel_launch(void* const* d_in, const int* in_sizes, int n_in,
                              void* d_out, int out_size, void* d_ws, size_t ws_size,
                              hipStream_t stream) {
    const float* x     = (const float*)d_in[0];
    const int*   mask  = (const int*)  d_in[1];
    const float* wq    = (const float*)d_in[2];
    const float* wk    = (const float*)d_in[3];
    const float* wv    = (const float*)d_in[4];
    const float* w_out = (const float*)d_in[5];
    const float* b_out = (const float*)d_in[6];
    const float* ff_w1 = (const float*)d_in[7];
    const float* ff_b1 = (const float*)d_in[8];
    const float* ff_w2 = (const float*)d_in[9];
    const float* ff_b2 = (const float*)d_in[10];
    const float* pr_w1 = (const float*)d_in[11];
    const float* pr_b1 = (const float*)d_in[12];
    const float* pr_w2 = (const float*)d_in[13];
    const float* pr_b2 = (const float*)d_in[14];
    float* out = (float*)d_out;

    char* ws = (char*)d_ws;
    const size_t MB = 1024ull*1024ull;
    const size_t KB = 1024ull;
    bf16*  qb    = (bf16*)(ws + 0*MB);
    bf16*  kbf   = (bf16*)(ws + 4*MB);
    bf16*  vbf   = (bf16*)(ws + 8*MB);
    bf16*  vtb   = (bf16*)(ws + 12*MB);
    unsigned short* attnb = (unsigned short*)(ws + 16*MB);   // 4MB bf16
    float* x1    = (float*)(ws + 20*MB);                     // 8MB
    float* y32   = (float*)(ws + 28*MB);                     // 8MB
    unsigned short* yb  = (unsigned short*)(ws + 36*MB);     // 4MB
    unsigned short* h1  = (unsigned short*)(ws + 0*MB);      // 16MB (qkv dead)
    float* s32   = (float*)(ws + 20*MB);                     // 8MB (x1 dead)
    unsigned short* s2b = (unsigned short*)(ws + 16*MB);     // 4MB (attnb dead)
    unsigned short* h2  = (unsigned short*)(ws + 0*MB);      // 16MB (h1 dead)
    unsigned short* woT = (unsigned short*)(ws + 40*MB);                // 128KB
    unsigned short* f1T = (unsigned short*)(ws + 40*MB + 128*KB);       // 512KB
    unsigned short* f2T = (unsigned short*)(ws + 40*MB + 640*KB);       // 512KB
    unsigned short* p1T = (unsigned short*)(ws + 40*MB + 1152*KB);      // 512KB
    unsigned short* p2T = (unsigned short*)(ws + 40*MB + 1664*KB);      // 512KB
    int*            mfl = (int*)           (ws + 40*MB + 2176*KB);      // 512B

    // 1. fused QKV (bf16, Q pre-scaled, K row-permuted) + weight prep + maskscan
    qkv_prep_kernel<<<1601, 256, 0, stream>>>(x, wq, wk, wv, qb, kbf, vbf,
                                              w_out, ff_w1, ff_w2, pr_w1, pr_w2,
                                              woT, f1T, f2T, p1T, p2T, mask, mfl);
    vtrans_kernel<<<B_*H_*(S_/256), 256, 0, stream>>>((const short*)vbf, (short*)vtb);
    // 2. MFMA flash attention (LDS-staged K/V, 128 q per block) -> bf16
    attn_mfma_kernel<<<B_*H_*S_/128, 256, 0, stream>>>(
        (const short*)qb, (const short*)kbf, (const short*)vtb, mask, mfl, attnb);
    // 3. out-proj + residual: x1 = x + attn @ w_out + b_out   (fp32 out)
    mgemm_kernel<64,64,0,1,1,0><<<(NTOK/64)*(E_/64), 256, 0, stream>>>(
        (const short*)attnb, (const short*)woT, b_out, x, x1, nullptr, NTOK, E_, E_);
    // 4. decomposition 1: y (fp32 + bf16)
    decomp_kernel<1,1><<<NTOK, 256, 0, stream>>>(x1, y32, yb);
    // 5. FFN
    mgemm_kernel<128,128,1,0,0,1><<<(NTOK/128)*(FF_/128), 256, 0, stream>>>(
        (const short*)yb, (const short*)f1T, ff_b1, nullptr, nullptr, h1, NTOK, FF_, E_);
    mgemm_kernel<64,64,0,1,1,0><<<(NTOK/64)*(E_/64), 256, 0, stream>>>(
        (const short*)h1, (const short*)f2T, ff_b2, y32, s32, nullptr, NTOK, E_, FF_);
    // 6. decomposition 2: s2 (bf16 only)
    decomp_kernel<0,1><<<NTOK, 256, 0, stream>>>(s32, nullptr, s2b);
    // 7. projection FFN
    mgemm_kernel<128,128,1,0,0,1><<<(NTOK/128)*(FF_/128), 256, 0, stream>>>(
        (const short*)s2b, (const short*)p1T, pr_b1, nullptr, nullptr, h2, NTOK, FF_, E_);
    mgemm_kernel<64,64,0,0,1,0><<<(NTOK/64)*(E_/64), 256, 0, stream>>>(
        (const short*)h2, (const short*)p2T, pr_b2, nullptr, out, nullptr, NTOK, E_, FF_);
}